// Round 4
// baseline (273.334 us; speedup 1.0000x reference)
//
#include <hip/hip_runtime.h>

// ManifoldAttentionLayer on MI355X — round 3
// R2 post-mortem: flash latency-bound (MfmaUtil 11%, occupancy 21% = 2 waves/
// SIMD, 2 barriers/iter + serial softmax chain). R3 flash rewrite:
//  - static-max softmax (scores bounded ~±16 in exp2 domain; exp2/fp32 safe):
//    no max reduce, no alpha rescale, no cross-lane ops in the K-loop.
//  - V stored TRANSPOSED + slot-permuted in global (GEMM z==2 epilogue), so
//    the PV A-fragment is one dwordx4 load: flash has ZERO LDS, ZERO barriers.
//  - grid (h, qb, b): all q-blocks of a head land on one XCD (linear%8==h%8),
//    K/V re-reads served by that XCD's L2.

using short8  = __attribute__((ext_vector_type(8))) short;
using short4v = __attribute__((ext_vector_type(4))) short;
using float4v = __attribute__((ext_vector_type(4))) float;

#define MFMA16(a, b, c) __builtin_amdgcn_mfma_f32_16x16x32_bf16((a), (b), (c), 0, 0, 0)

#define LOG2E 1.44269504088896f

static __device__ __forceinline__ short f2bf(float f) {
    union { float f; unsigned u; } v; v.f = f;
    unsigned r = v.u + 0x7fffu + ((v.u >> 16) & 1u);   // round-to-nearest-even
    return (short)(r >> 16);
}

// ---------------- 1a) x: fp32 -> bf16 ----------------
__global__ __launch_bounds__(256) void convert_bf16(const float* __restrict__ in,
                                                    short* __restrict__ out, int n4) {
    int idx = blockIdx.x * 256 + threadIdx.x;
    for (int i = idx; i < n4; i += gridDim.x * 256) {
        float4v v = *(const float4v*)(in + (size_t)i * 4);
        short4v o;
        o.x = f2bf(v.x); o.y = f2bf(v.y); o.z = f2bf(v.z); o.w = f2bf(v.w);
        *(short4v*)(out + (size_t)i * 4) = o;
    }
}

// ---------------- 1b) 4 weight matrices: fp32 -> bf16 ----------------
__global__ __launch_bounds__(256) void convert_w4(const float* __restrict__ w0,
                                                  const float* __restrict__ w1,
                                                  const float* __restrict__ w2,
                                                  const float* __restrict__ w3,
                                                  short* __restrict__ out) {
    int z = blockIdx.y;
    const float* w = (z == 0) ? w0 : (z == 1) ? w1 : (z == 2) ? w2 : w3;
    short* o = out + (size_t)z * 1048576;
    int idx = blockIdx.x * 256 + threadIdx.x;
    for (int i = idx; i < 262144; i += gridDim.x * 256) {
        float4v v = *(const float4v*)(w + (size_t)i * 4);
        short4v s;
        s.x = f2bf(v.x); s.y = f2bf(v.y); s.z = f2bf(v.z); s.w = f2bf(v.w);
        *(short4v*)(o + (size_t)i * 4) = s;
    }
}

// ---------------- 2) gram = harmonics @ harmonicsT ----------------
__global__ __launch_bounds__(256) void gram_kernel(const float* __restrict__ harm,
                                                   float* __restrict__ gram) {
    int b = blockIdx.x;
    __shared__ float hs[64][32];
    int tid = threadIdx.x;
    for (int i = tid; i < 2048; i += 256) hs[i >> 5][i & 31] = harm[(size_t)b * 2048 + i];
    __syncthreads();
    for (int i = tid; i < 4096; i += 256) {
        int m = i >> 6, n = i & 63;
        float s = 0.f;
        #pragma unroll
        for (int k = 0; k < 32; k++) s += hs[m][k] * hs[n][k];
        gram[(size_t)b * 4096 + i] = s;
    }
}

// ---------------- 4) fill augmented dims of Q'/K' (bias fold) ----------------
__global__ __launch_bounds__(256) void fill_aug(const float* __restrict__ gram,
                                                short* __restrict__ Qp,
                                                short* __restrict__ Kp) {
    int b  = blockIdx.y;
    int lc = blockIdx.x;
    int tid = threadIdx.x;
    int ll = tid >> 3;
    int d8 = (tid & 7) * 8;
    int l  = lc * 32 + ll;

    float src = (l + 0.5f) * 0.0625f - 0.5f;
    if (src < 0.f) src = 0.f;
    int r0 = (int)floorf(src); if (r0 > 63) r0 = 63;
    int r1 = r0 + 1;           if (r1 > 63) r1 = 63;
    float wy = src - (float)r0;

    const float* g0 = gram + ((size_t)b * 64 + r0) * 64 + d8;
    const float* g1 = gram + ((size_t)b * 64 + r1) * 64 + d8;
    short8 qa, ka;
    #pragma unroll
    for (int j = 0; j < 8; j++)
        qa[j] = f2bf(0.1f * LOG2E * (g0[j] * (1.f - wy) + g1[j] * wy));
    #pragma unroll
    for (int j = 0; j < 8; j++) {
        float vv = 0.f;
        if (d8 + j == r0) vv += 1.f - wy;
        if (d8 + j == r1) vv += wy;
        ka[j] = f2bf(vv);
    }
    for (int h = 0; h < 16; h++) {
        size_t base = (((size_t)(b * 16 + h) * 1024 + l) << 7) + 64 + d8;
        *(short8*)(Qp + base) = qa;
        *(short8*)(Kp + base) = ka;
    }
}

// ---------------- 3/6) GEMM ----------------
// MODE 0: z picks q/k/v. V written TRANSPOSED + slot-permuted: Vp[bh][d][slot(l)],
// slot(l) = (l&~31) | ((l>>2)&3)<<3 | ((l>>4)&1)<<2 | (l&3)  (matches the PV
// B-fragment key order so the flash A-frag is one contiguous dwordx4).
template <int MODE>
__global__ __launch_bounds__(256, 2) void gemm_kernel(
    const short* __restrict__ A,
    const short* __restrict__ Wb,
    const float* __restrict__ B0, const float* __restrict__ B1, const float* __restrict__ B2,
    short* __restrict__ Qp, short* __restrict__ Kp, short* __restrict__ Vp,
    float* __restrict__ outF) {
    const int z = blockIdx.z;
    const short* W  = Wb + (size_t)z * 1048576;
    const float* Bs = (z == 0) ? B0 : ((z == 1) ? B1 : B2);

    __shared__ short As[128][40];
    __shared__ short Bsh[128][40];

    const int tid  = threadIdx.x;
    const int lane = tid & 63;
    const int wv   = tid >> 6;
    const int wm   = (wv >> 1) * 64;
    const int wn   = (wv & 1) * 64;
    const int l16  = lane & 15;
    const int quad = lane >> 4;
    const int bm   = blockIdx.x * 128;
    const int bn   = blockIdx.y * 128;

    float4v zero4 = {0.f, 0.f, 0.f, 0.f};
    float4v acc[4][4];
    #pragma unroll
    for (int i = 0; i < 4; i++)
        #pragma unroll
        for (int j = 0; j < 4; j++) acc[i][j] = zero4;

    for (int kt = 0; kt < 1024; kt += 32) {
        #pragma unroll
        for (int c = tid; c < 512; c += 256) {
            int r = c >> 2, c8 = (c & 3) * 8;
            *(short8*)&As[r][c8]  = *(const short8*)(A + (size_t)(bm + r) * 1024 + kt + c8);
            *(short8*)&Bsh[r][c8] = *(const short8*)(W + (size_t)(bn + r) * 1024 + kt + c8);
        }
        __syncthreads();
        short8 af[4], bfr[4];
        #pragma unroll
        for (int mt = 0; mt < 4; mt++) af[mt]  = *(const short8*)&As[wm + mt * 16 + l16][quad * 8];
        #pragma unroll
        for (int nt = 0; nt < 4; nt++) bfr[nt] = *(const short8*)&Bsh[wn + nt * 16 + l16][quad * 8];
        #pragma unroll
        for (int mt = 0; mt < 4; mt++)
            #pragma unroll
            for (int nt = 0; nt < 4; nt++)
                acc[mt][nt] = MFMA16(af[mt], bfr[nt], acc[mt][nt]);
        __syncthreads();
    }

    #pragma unroll
    for (int mt = 0; mt < 4; mt++)
        #pragma unroll
        for (int nt = 0; nt < 4; nt++) {
            int col = bn + wn + nt * 16 + l16;
            float bias = Bs[col];
            #pragma unroll
            for (int r = 0; r < 4; r++) {
                int row = bm + wm + mt * 16 + quad * 4 + r;
                float val = acc[mt][nt][r] + bias;
                if (MODE == 1) {
                    outF[(size_t)row * 1024 + col] = val;
                } else {
                    int b = row >> 10, l = row & 1023;
                    int h = col >> 6,  d = col & 63;
                    size_t bhl = (size_t)(b * 16 + h) * 1024 + l;
                    if (z == 0)      Qp[(bhl << 7) + d] = f2bf(val * (0.125f * LOG2E));
                    else if (z == 1) Kp[(bhl << 7) + d] = f2bf(val);
                    else {
                        int slot = (l & ~31) | (((l >> 2) & 3) << 3) |
                                   (((l >> 4) & 1) << 2) | (l & 3);
                        Vp[(((size_t)(b * 16 + h) * 64 + d) << 10) + slot] = f2bf(val);
                    }
                }
            }
        }
}

// ---------------- 5) flash attention: no LDS, no barriers, static max ----------------
// grid (16 h, 8 qb, 4 b); 256 thr = 4 waves x 32 q.
__global__ __launch_bounds__(256, 2) void flash_kernel(const short* __restrict__ Qp,
                                                       const short* __restrict__ Kp,
                                                       const short* __restrict__ Vp,
                                                       short* __restrict__ AO) {
    const int h  = blockIdx.x;
    const int qb = blockIdx.y;
    const int b  = blockIdx.z;
    const int tid  = threadIdx.x;
    const int lane = tid & 63;
    const int w    = tid >> 6;
    const int l16  = lane & 15;
    const int quad = lane >> 4;
    const size_t bh = (size_t)(b * 16 + h);

    // Q fragments (B-operand): lane l16 -> q row, k = quad*8 + j
    short8 qf[2][4];
    #pragma unroll
    for (int n = 0; n < 2; n++) {
        const short* Qb = Qp + ((bh * 1024 + qb * 128 + w * 32 + n * 16 + l16) << 7) + quad * 8;
        #pragma unroll
        for (int c = 0; c < 4; c++) qf[n][c] = *(const short8*)(Qb + c * 32);
    }

    const short* Kbase = Kp + (bh << 17) + (l16 << 7) + quad * 8;   // + key*128 + c*32
    const short* Vbase = Vp + (bh << 16) + (l16 << 10) + quad * 8;  // + d16*16384 + slotcol

    float4v zero4 = {0.f, 0.f, 0.f, 0.f};
    float4v o_acc[4][2];
    #pragma unroll
    for (int mt = 0; mt < 4; mt++)
        #pragma unroll
        for (int n = 0; n < 2; n++) o_acc[mt][n] = zero4;
    float l_part[2] = {0.f, 0.f};

    for (int kt = 0; kt < 16; kt++) {
        const int k0 = kt * 64;
        // K fragments: 16 dwordx4 loads (independent)
        short8 kf[4][4];
        #pragma unroll
        for (int mt = 0; mt < 4; mt++)
            #pragma unroll
            for (int c = 0; c < 4; c++)
                kf[mt][c] = *(const short8*)(Kbase + ((size_t)(k0 + mt * 16) << 7) + c * 32);
        // V^T fragments (slot-permuted layout -> contiguous): 8 dwordx4 loads
        short8 vf[4][2];
        #pragma unroll
        for (int mt = 0; mt < 4; mt++)
            #pragma unroll
            for (int g = 0; g < 2; g++)
                vf[mt][g] = *(const short8*)(Vbase + ((size_t)mt << 14) + k0 + g * 32);

        // S^T = K·Q^T (C-layout: col=lane16=q, row=key=mt*16+quad*4+r)
        float4v s[4][2];
        #pragma unroll
        for (int mt = 0; mt < 4; mt++)
            #pragma unroll
            for (int n = 0; n < 2; n++) {
                s[mt][n] = zero4;
                #pragma unroll
                for (int c = 0; c < 4; c++)
                    s[mt][n] = MFMA16(kf[mt][c], qf[n][c], s[mt][n]);
            }

        // p = exp2(s)  (log2e folded into Q scales; bounded, no max needed)
        #pragma unroll
        for (int mt = 0; mt < 4; mt++)
            #pragma unroll
            for (int n = 0; n < 2; n++)
                #pragma unroll
                for (int r = 0; r < 4; r++) {
                    float p = __builtin_exp2f(s[mt][n][r]);
                    s[mt][n][r] = p;
                    l_part[n] += p;
                }

        // O^T += V^T · P^T
        #pragma unroll
        for (int g = 0; g < 2; g++) {
            short8 pf[2];
            #pragma unroll
            for (int n = 0; n < 2; n++)
                #pragma unroll
                for (int j = 0; j < 4; j++) {
                    pf[n][j]     = f2bf(s[2 * g][n][j]);
                    pf[n][4 + j] = f2bf(s[2 * g + 1][n][j]);
                }
            #pragma unroll
            for (int mt = 0; mt < 4; mt++)
                #pragma unroll
                for (int n = 0; n < 2; n++)
                    o_acc[mt][n] = MFMA16(vf[mt][g], pf[n], o_acc[mt][n]);
        }
    }

    // epilogue: reduce l across quads (lanes with same l16), normalize, store
    #pragma unroll
    for (int n = 0; n < 2; n++) {
        float l = l_part[n];
        l += __shfl_xor(l, 16, 64);
        l += __shfl_xor(l, 32, 64);
        float inv = 1.0f / l;
        int row = b * 1024 + qb * 128 + w * 32 + n * 16 + l16;
        #pragma unroll
        for (int mt = 0; mt < 4; mt++) {
            short4v ov;
            #pragma unroll
            for (int r = 0; r < 4; r++) ov[r] = f2bf(o_acc[mt][n][r] * inv);
            *(short4v*)(AO + (size_t)row * 1024 + h * 64 + mt * 16 + quad * 4) = ov;
        }
    }
}

extern "C" void kernel_launch(void* const* d_in, const int* in_sizes, int n_in,
                              void* d_out, int out_size, void* d_ws, size_t ws_size,
                              hipStream_t stream) {
    const float* x    = (const float*)d_in[0];
    const float* harm = (const float*)d_in[1];
    const float* wq   = (const float*)d_in[2];
    const float* bq   = (const float*)d_in[3];
    const float* wk   = (const float*)d_in[4];
    const float* bk   = (const float*)d_in[5];
    const float* wv   = (const float*)d_in[6];
    const float* bv   = (const float*)d_in[7];
    const float* wo   = (const float*)d_in[8];
    const float* bo   = (const float*)d_in[9];
    float* outF = (float*)d_out;

    short* xb   = (short*)d_ws;
    short* Qp   = xb + (size_t)4 * 1048576;
    short* Kp   = Qp + (size_t)8 * 1048576;
    short* Vp   = Kp + (size_t)8 * 1048576;
    short* Wqkv = Vp + (size_t)4 * 1048576;
    short* Wob  = Wqkv + (size_t)3 * 1048576;
    float* gram = (float*)(Wob + 1048576);
    short* AO   = xb;   // alias: xb consumed by QKV GEMM before flash writes AO

    convert_bf16<<<dim3(1024), dim3(256), 0, stream>>>(x, xb, 1048576);
    convert_w4<<<dim3(256, 4), dim3(256), 0, stream>>>(wq, wk, wv, wo, Wqkv);
    gram_kernel<<<dim3(4), dim3(256), 0, stream>>>(harm, gram);
    gemm_kernel<0><<<dim3(32, 8, 3), dim3(256), 0, stream>>>(
        xb, Wqkv, bq, bk, bv, Qp, Kp, Vp, nullptr);
    fill_aug<<<dim3(32, 4), dim3(256), 0, stream>>>(gram, Qp, Kp);
    flash_kernel<<<dim3(16, 8, 4), dim3(256), 0, stream>>>(Qp, Kp, Vp, AO);
    gemm_kernel<1><<<dim3(32, 8, 1), dim3(256), 0, stream>>>(
        AO, Wob, bo, nullptr, nullptr, nullptr, nullptr, nullptr, outF);
}

// Round 5
// 267.384 us; speedup vs baseline: 1.0223x; 1.0223x over previous
//
#include <hip/hip_runtime.h>

// ManifoldAttentionLayer on MI355X — round 4
// R3 post-mortem: flash loads were SERIALIZED by the register allocator
// (VGPR_Count=68: compiler targeted 7 waves/SIMD occupancy the 512-block grid
// can never provide, so the 24 dwordx4 loads/iter could not stay in flight;
// ~16 serial L2 hits x 250cyc x 16 iters matches the 98us measured).
// R4 fix (single variable): amdgpu_waves_per_eu(2,2) on flash_kernel ->
// allocator may use up to 256 VGPR, keeping all fragment loads in flight.

using short8  = __attribute__((ext_vector_type(8))) short;
using short4v = __attribute__((ext_vector_type(4))) short;
using float4v = __attribute__((ext_vector_type(4))) float;

#define MFMA16(a, b, c) __builtin_amdgcn_mfma_f32_16x16x32_bf16((a), (b), (c), 0, 0, 0)

#define LOG2E 1.44269504088896f

static __device__ __forceinline__ short f2bf(float f) {
    union { float f; unsigned u; } v; v.f = f;
    unsigned r = v.u + 0x7fffu + ((v.u >> 16) & 1u);   // round-to-nearest-even
    return (short)(r >> 16);
}

// ---------------- 1a) x: fp32 -> bf16 ----------------
__global__ __launch_bounds__(256) void convert_bf16(const float* __restrict__ in,
                                                    short* __restrict__ out, int n4) {
    int idx = blockIdx.x * 256 + threadIdx.x;
    for (int i = idx; i < n4; i += gridDim.x * 256) {
        float4v v = *(const float4v*)(in + (size_t)i * 4);
        short4v o;
        o.x = f2bf(v.x); o.y = f2bf(v.y); o.z = f2bf(v.z); o.w = f2bf(v.w);
        *(short4v*)(out + (size_t)i * 4) = o;
    }
}

// ---------------- 1b) 4 weight matrices: fp32 -> bf16 ----------------
__global__ __launch_bounds__(256) void convert_w4(const float* __restrict__ w0,
                                                  const float* __restrict__ w1,
                                                  const float* __restrict__ w2,
                                                  const float* __restrict__ w3,
                                                  short* __restrict__ out) {
    int z = blockIdx.y;
    const float* w = (z == 0) ? w0 : (z == 1) ? w1 : (z == 2) ? w2 : w3;
    short* o = out + (size_t)z * 1048576;
    int idx = blockIdx.x * 256 + threadIdx.x;
    for (int i = idx; i < 262144; i += gridDim.x * 256) {
        float4v v = *(const float4v*)(w + (size_t)i * 4);
        short4v s;
        s.x = f2bf(v.x); s.y = f2bf(v.y); s.z = f2bf(v.z); s.w = f2bf(v.w);
        *(short4v*)(o + (size_t)i * 4) = s;
    }
}

// ---------------- 2) gram = harmonics @ harmonicsT ----------------
__global__ __launch_bounds__(256) void gram_kernel(const float* __restrict__ harm,
                                                   float* __restrict__ gram) {
    int b = blockIdx.x;
    __shared__ float hs[64][32];
    int tid = threadIdx.x;
    for (int i = tid; i < 2048; i += 256) hs[i >> 5][i & 31] = harm[(size_t)b * 2048 + i];
    __syncthreads();
    for (int i = tid; i < 4096; i += 256) {
        int m = i >> 6, n = i & 63;
        float s = 0.f;
        #pragma unroll
        for (int k = 0; k < 32; k++) s += hs[m][k] * hs[n][k];
        gram[(size_t)b * 4096 + i] = s;
    }
}

// ---------------- 4) fill augmented dims of Q'/K' (bias fold) ----------------
__global__ __launch_bounds__(256) void fill_aug(const float* __restrict__ gram,
                                                short* __restrict__ Qp,
                                                short* __restrict__ Kp) {
    int b  = blockIdx.y;
    int lc = blockIdx.x;
    int tid = threadIdx.x;
    int ll = tid >> 3;
    int d8 = (tid & 7) * 8;
    int l  = lc * 32 + ll;

    float src = (l + 0.5f) * 0.0625f - 0.5f;
    if (src < 0.f) src = 0.f;
    int r0 = (int)floorf(src); if (r0 > 63) r0 = 63;
    int r1 = r0 + 1;           if (r1 > 63) r1 = 63;
    float wy = src - (float)r0;

    const float* g0 = gram + ((size_t)b * 64 + r0) * 64 + d8;
    const float* g1 = gram + ((size_t)b * 64 + r1) * 64 + d8;
    short8 qa, ka;
    #pragma unroll
    for (int j = 0; j < 8; j++)
        qa[j] = f2bf(0.1f * LOG2E * (g0[j] * (1.f - wy) + g1[j] * wy));
    #pragma unroll
    for (int j = 0; j < 8; j++) {
        float vv = 0.f;
        if (d8 + j == r0) vv += 1.f - wy;
        if (d8 + j == r1) vv += wy;
        ka[j] = f2bf(vv);
    }
    for (int h = 0; h < 16; h++) {
        size_t base = (((size_t)(b * 16 + h) * 1024 + l) << 7) + 64 + d8;
        *(short8*)(Qp + base) = qa;
        *(short8*)(Kp + base) = ka;
    }
}

// ---------------- 3/6) GEMM ----------------
// MODE 0: z picks q/k/v. V written TRANSPOSED + slot-permuted: Vp[bh][d][slot(l)],
// slot(l) = (l&~31) | ((l>>2)&3)<<3 | ((l>>4)&1)<<2 | (l&3).
template <int MODE>
__global__ __launch_bounds__(256, 2) void gemm_kernel(
    const short* __restrict__ A,
    const short* __restrict__ Wb,
    const float* __restrict__ B0, const float* __restrict__ B1, const float* __restrict__ B2,
    short* __restrict__ Qp, short* __restrict__ Kp, short* __restrict__ Vp,
    float* __restrict__ outF) {
    const int z = blockIdx.z;
    const short* W  = Wb + (size_t)z * 1048576;
    const float* Bs = (z == 0) ? B0 : ((z == 1) ? B1 : B2);

    __shared__ short As[128][40];
    __shared__ short Bsh[128][40];

    const int tid  = threadIdx.x;
    const int lane = tid & 63;
    const int wv   = tid >> 6;
    const int wm   = (wv >> 1) * 64;
    const int wn   = (wv & 1) * 64;
    const int l16  = lane & 15;
    const int quad = lane >> 4;
    const int bm   = blockIdx.x * 128;
    const int bn   = blockIdx.y * 128;

    float4v zero4 = {0.f, 0.f, 0.f, 0.f};
    float4v acc[4][4];
    #pragma unroll
    for (int i = 0; i < 4; i++)
        #pragma unroll
        for (int j = 0; j < 4; j++) acc[i][j] = zero4;

    for (int kt = 0; kt < 1024; kt += 32) {
        #pragma unroll
        for (int c = tid; c < 512; c += 256) {
            int r = c >> 2, c8 = (c & 3) * 8;
            *(short8*)&As[r][c8]  = *(const short8*)(A + (size_t)(bm + r) * 1024 + kt + c8);
            *(short8*)&Bsh[r][c8] = *(const short8*)(W + (size_t)(bn + r) * 1024 + kt + c8);
        }
        __syncthreads();
        short8 af[4], bfr[4];
        #pragma unroll
        for (int mt = 0; mt < 4; mt++) af[mt]  = *(const short8*)&As[wm + mt * 16 + l16][quad * 8];
        #pragma unroll
        for (int nt = 0; nt < 4; nt++) bfr[nt] = *(const short8*)&Bsh[wn + nt * 16 + l16][quad * 8];
        #pragma unroll
        for (int mt = 0; mt < 4; mt++)
            #pragma unroll
            for (int nt = 0; nt < 4; nt++)
                acc[mt][nt] = MFMA16(af[mt], bfr[nt], acc[mt][nt]);
        __syncthreads();
    }

    #pragma unroll
    for (int mt = 0; mt < 4; mt++)
        #pragma unroll
        for (int nt = 0; nt < 4; nt++) {
            int col = bn + wn + nt * 16 + l16;
            float bias = Bs[col];
            #pragma unroll
            for (int r = 0; r < 4; r++) {
                int row = bm + wm + mt * 16 + quad * 4 + r;
                float val = acc[mt][nt][r] + bias;
                if (MODE == 1) {
                    outF[(size_t)row * 1024 + col] = val;
                } else {
                    int b = row >> 10, l = row & 1023;
                    int h = col >> 6,  d = col & 63;
                    size_t bhl = (size_t)(b * 16 + h) * 1024 + l;
                    if (z == 0)      Qp[(bhl << 7) + d] = f2bf(val * (0.125f * LOG2E));
                    else if (z == 1) Kp[(bhl << 7) + d] = f2bf(val);
                    else {
                        int slot = (l & ~31) | (((l >> 2) & 3) << 3) |
                                   (((l >> 4) & 1) << 2) | (l & 3);
                        Vp[(((size_t)(b * 16 + h) * 64 + d) << 10) + slot] = f2bf(val);
                    }
                }
            }
        }
}

// ---------------- 5) flash attention: no LDS, no barriers, static max ----------------
// grid (16 h, 8 qb, 4 b); 256 thr = 4 waves x 32 q.
// waves_per_eu(2,2): the grid provides exactly 2 waves/SIMD; let the register
// allocator use the full 256-VGPR budget so all 24 fragment loads stay in flight.
__global__ __attribute__((amdgpu_flat_work_group_size(256, 256),
                          amdgpu_waves_per_eu(2, 2)))
void flash_kernel(const short* __restrict__ Qp,
                  const short* __restrict__ Kp,
                  const short* __restrict__ Vp,
                  short* __restrict__ AO) {
    const int h  = blockIdx.x;
    const int qb = blockIdx.y;
    const int b  = blockIdx.z;
    const int tid  = threadIdx.x;
    const int lane = tid & 63;
    const int w    = tid >> 6;
    const int l16  = lane & 15;
    const int quad = lane >> 4;
    const size_t bh = (size_t)(b * 16 + h);

    // Q fragments (B-operand): lane l16 -> q row, k = quad*8 + j
    short8 qf[2][4];
    #pragma unroll
    for (int n = 0; n < 2; n++) {
        const short* Qb = Qp + ((bh * 1024 + qb * 128 + w * 32 + n * 16 + l16) << 7) + quad * 8;
        #pragma unroll
        for (int c = 0; c < 4; c++) qf[n][c] = *(const short8*)(Qb + c * 32);
    }

    const short* Kbase = Kp + (bh << 17) + (l16 << 7) + quad * 8;   // + key*128 + c*32
    const short* Vbase = Vp + (bh << 16) + (l16 << 10) + quad * 8;  // + d16*16384 + slotcol

    float4v zero4 = {0.f, 0.f, 0.f, 0.f};
    float4v o_acc[4][2];
    #pragma unroll
    for (int mt = 0; mt < 4; mt++)
        #pragma unroll
        for (int n = 0; n < 2; n++) o_acc[mt][n] = zero4;
    float l_part[2] = {0.f, 0.f};

    for (int kt = 0; kt < 16; kt++) {
        const int k0 = kt * 64;
        // K fragments: 16 dwordx4 loads (independent)
        short8 kf[4][4];
        #pragma unroll
        for (int mt = 0; mt < 4; mt++)
            #pragma unroll
            for (int c = 0; c < 4; c++)
                kf[mt][c] = *(const short8*)(Kbase + ((size_t)(k0 + mt * 16) << 7) + c * 32);
        // V^T fragments (slot-permuted layout -> contiguous): 8 dwordx4 loads
        short8 vf[4][2];
        #pragma unroll
        for (int mt = 0; mt < 4; mt++)
            #pragma unroll
            for (int g = 0; g < 2; g++)
                vf[mt][g] = *(const short8*)(Vbase + ((size_t)mt << 14) + k0 + g * 32);

        // S^T = K·Q^T (C-layout: col=lane16=q, row=key=mt*16+quad*4+r)
        float4v s[4][2];
        #pragma unroll
        for (int mt = 0; mt < 4; mt++)
            #pragma unroll
            for (int n = 0; n < 2; n++) {
                s[mt][n] = zero4;
                #pragma unroll
                for (int c = 0; c < 4; c++)
                    s[mt][n] = MFMA16(kf[mt][c], qf[n][c], s[mt][n]);
            }

        // p = exp2(s)  (log2e folded into Q scales; bounded, no max needed)
        #pragma unroll
        for (int mt = 0; mt < 4; mt++)
            #pragma unroll
            for (int n = 0; n < 2; n++)
                #pragma unroll
                for (int r = 0; r < 4; r++) {
                    float p = __builtin_exp2f(s[mt][n][r]);
                    s[mt][n][r] = p;
                    l_part[n] += p;
                }

        // O^T += V^T · P^T
        #pragma unroll
        for (int g = 0; g < 2; g++) {
            short8 pf[2];
            #pragma unroll
            for (int n = 0; n < 2; n++)
                #pragma unroll
                for (int j = 0; j < 4; j++) {
                    pf[n][j]     = f2bf(s[2 * g][n][j]);
                    pf[n][4 + j] = f2bf(s[2 * g + 1][n][j]);
                }
            #pragma unroll
            for (int mt = 0; mt < 4; mt++)
                #pragma unroll
                for (int n = 0; n < 2; n++)
                    o_acc[mt][n] = MFMA16(vf[mt][g], pf[n], o_acc[mt][n]);
        }
    }

    // epilogue: reduce l across quads (lanes with same l16), normalize, store
    #pragma unroll
    for (int n = 0; n < 2; n++) {
        float l = l_part[n];
        l += __shfl_xor(l, 16, 64);
        l += __shfl_xor(l, 32, 64);
        float inv = 1.0f / l;
        int row = b * 1024 + qb * 128 + w * 32 + n * 16 + l16;
        #pragma unroll
        for (int mt = 0; mt < 4; mt++) {
            short4v ov;
            #pragma unroll
            for (int r = 0; r < 4; r++) ov[r] = f2bf(o_acc[mt][n][r] * inv);
            *(short4v*)(AO + (size_t)row * 1024 + h * 64 + mt * 16 + quad * 4) = ov;
        }
    }
}

extern "C" void kernel_launch(void* const* d_in, const int* in_sizes, int n_in,
                              void* d_out, int out_size, void* d_ws, size_t ws_size,
                              hipStream_t stream) {
    const float* x    = (const float*)d_in[0];
    const float* harm = (const float*)d_in[1];
    const float* wq   = (const float*)d_in[2];
    const float* bq   = (const float*)d_in[3];
    const float* wk   = (const float*)d_in[4];
    const float* bk   = (const float*)d_in[5];
    const float* wv   = (const float*)d_in[6];
    const float* bv   = (const float*)d_in[7];
    const float* wo   = (const float*)d_in[8];
    const float* bo   = (const float*)d_in[9];
    float* outF = (float*)d_out;

    short* xb   = (short*)d_ws;
    short* Qp   = xb + (size_t)4 * 1048576;
    short* Kp   = Qp + (size_t)8 * 1048576;
    short* Vp   = Kp + (size_t)8 * 1048576;
    short* Wqkv = Vp + (size_t)4 * 1048576;
    short* Wob  = Wqkv + (size_t)3 * 1048576;
    float* gram = (float*)(Wob + 1048576);
    short* AO   = xb;   // alias: xb consumed by QKV GEMM before flash writes AO

    convert_bf16<<<dim3(1024), dim3(256), 0, stream>>>(x, xb, 1048576);
    convert_w4<<<dim3(256, 4), dim3(256), 0, stream>>>(wq, wk, wv, wo, Wqkv);
    gram_kernel<<<dim3(4), dim3(256), 0, stream>>>(harm, gram);
    gemm_kernel<0><<<dim3(32, 8, 3), dim3(256), 0, stream>>>(
        xb, Wqkv, bq, bk, bv, Qp, Kp, Vp, nullptr);
    fill_aug<<<dim3(32, 4), dim3(256), 0, stream>>>(gram, Qp, Kp);
    flash_kernel<<<dim3(16, 8, 4), dim3(256), 0, stream>>>(Qp, Kp, Vp, AO);
    gemm_kernel<1><<<dim3(32, 8, 1), dim3(256), 0, stream>>>(
        AO, Wob, bo, nullptr, nullptr, nullptr, nullptr, nullptr, outF);
}

// Round 6
// 217.192 us; speedup vs baseline: 1.2585x; 1.2311x over previous
//
#include <hip/hip_runtime.h>

// ManifoldAttentionLayer on MI355X — round 5
// R4 post-mortem: flash was VMEM-bound by structure, not just regalloc: every
// wave loaded the whole 24KB K/V tile (4x duplicated per block, 192KB/iter/CU)
// with per-iter load->wait->MFMA serialization. R5: m97-style staging —
// global_load_lds(16B) double-buffered K+V tiles (24KB DMA/block/iter, zero
// VGPR cost, latency hidden behind compute), ds_read_b128 fragments with an
// XOR swizzle applied on the DMA *source* side (LDS stays lane-linear as the
// DMA demands; reads land 2-way bank-aliased = free). bf16 pack via v_perm.

using short8  = __attribute__((ext_vector_type(8))) short;
using short4v = __attribute__((ext_vector_type(4))) short;
using float4v = __attribute__((ext_vector_type(4))) float;

#define MFMA16(a, b, c) __builtin_amdgcn_mfma_f32_16x16x32_bf16((a), (b), (c), 0, 0, 0)

#define LOG2E 1.44269504088896f

static __device__ __forceinline__ short f2bf(float f) {
    union { float f; unsigned u; } v; v.f = f;
    unsigned r = v.u + 0x7fffu + ((v.u >> 16) & 1u);   // round-to-nearest-even
    return (short)(r >> 16);
}

// pack two f32 -> packed bf16 pair (round-half-up; differs from RNE only on
// exact ties, +1ulp, negligible): 2 adds + 1 v_perm.
static __device__ __forceinline__ unsigned pack2bf(float lo, float hi) {
    union { float f; unsigned u; } a, b;
    a.f = lo; b.f = hi;
    return __builtin_amdgcn_perm(b.u + 0x8000u, a.u + 0x8000u, 0x07060302u);
}

// async global->LDS DMA, 16B per lane; LDS dest = uniform base + lane*16.
static __device__ __forceinline__ void dma16(const short* g, short* l) {
    __builtin_amdgcn_global_load_lds((const __attribute__((address_space(1))) void*)g,
                                     (__attribute__((address_space(3))) void*)l, 16, 0, 0);
}

// ---------------- 1a) x: fp32 -> bf16 ----------------
__global__ __launch_bounds__(256) void convert_bf16(const float* __restrict__ in,
                                                    short* __restrict__ out, int n4) {
    int idx = blockIdx.x * 256 + threadIdx.x;
    for (int i = idx; i < n4; i += gridDim.x * 256) {
        float4v v = *(const float4v*)(in + (size_t)i * 4);
        short4v o;
        o.x = f2bf(v.x); o.y = f2bf(v.y); o.z = f2bf(v.z); o.w = f2bf(v.w);
        *(short4v*)(out + (size_t)i * 4) = o;
    }
}

// ---------------- 1b) 4 weight matrices: fp32 -> bf16 ----------------
__global__ __launch_bounds__(256) void convert_w4(const float* __restrict__ w0,
                                                  const float* __restrict__ w1,
                                                  const float* __restrict__ w2,
                                                  const float* __restrict__ w3,
                                                  short* __restrict__ out) {
    int z = blockIdx.y;
    const float* w = (z == 0) ? w0 : (z == 1) ? w1 : (z == 2) ? w2 : w3;
    short* o = out + (size_t)z * 1048576;
    int idx = blockIdx.x * 256 + threadIdx.x;
    for (int i = idx; i < 262144; i += gridDim.x * 256) {
        float4v v = *(const float4v*)(w + (size_t)i * 4);
        short4v s;
        s.x = f2bf(v.x); s.y = f2bf(v.y); s.z = f2bf(v.z); s.w = f2bf(v.w);
        *(short4v*)(o + (size_t)i * 4) = s;
    }
}

// ---------------- 2) gram = harmonics @ harmonicsT ----------------
__global__ __launch_bounds__(256) void gram_kernel(const float* __restrict__ harm,
                                                   float* __restrict__ gram) {
    int b = blockIdx.x;
    __shared__ float hs[64][32];
    int tid = threadIdx.x;
    for (int i = tid; i < 2048; i += 256) hs[i >> 5][i & 31] = harm[(size_t)b * 2048 + i];
    __syncthreads();
    for (int i = tid; i < 4096; i += 256) {
        int m = i >> 6, n = i & 63;
        float s = 0.f;
        #pragma unroll
        for (int k = 0; k < 32; k++) s += hs[m][k] * hs[n][k];
        gram[(size_t)b * 4096 + i] = s;
    }
}

// ---------------- 4) fill augmented dims of Q'/K' (bias fold) ----------------
__global__ __launch_bounds__(256) void fill_aug(const float* __restrict__ gram,
                                                short* __restrict__ Qp,
                                                short* __restrict__ Kp) {
    int b  = blockIdx.y;
    int lc = blockIdx.x;
    int tid = threadIdx.x;
    int ll = tid >> 3;
    int d8 = (tid & 7) * 8;
    int l  = lc * 32 + ll;

    float src = (l + 0.5f) * 0.0625f - 0.5f;
    if (src < 0.f) src = 0.f;
    int r0 = (int)floorf(src); if (r0 > 63) r0 = 63;
    int r1 = r0 + 1;           if (r1 > 63) r1 = 63;
    float wy = src - (float)r0;

    const float* g0 = gram + ((size_t)b * 64 + r0) * 64 + d8;
    const float* g1 = gram + ((size_t)b * 64 + r1) * 64 + d8;
    short8 qa, ka;
    #pragma unroll
    for (int j = 0; j < 8; j++)
        qa[j] = f2bf(0.1f * LOG2E * (g0[j] * (1.f - wy) + g1[j] * wy));
    #pragma unroll
    for (int j = 0; j < 8; j++) {
        float vv = 0.f;
        if (d8 + j == r0) vv += 1.f - wy;
        if (d8 + j == r1) vv += wy;
        ka[j] = f2bf(vv);
    }
    for (int h = 0; h < 16; h++) {
        size_t base = (((size_t)(b * 16 + h) * 1024 + l) << 7) + 64 + d8;
        *(short8*)(Qp + base) = qa;
        *(short8*)(Kp + base) = ka;
    }
}

// ---------------- 3/6) GEMM ----------------
// MODE 0: z picks q/k/v. V written TRANSPOSED + slot-permuted: Vp[bh][d][slot(l)],
// slot(l) = (l&~31) | ((l>>2)&3)<<3 | ((l>>4)&1)<<2 | (l&3).
template <int MODE>
__global__ __launch_bounds__(256, 2) void gemm_kernel(
    const short* __restrict__ A,
    const short* __restrict__ Wb,
    const float* __restrict__ B0, const float* __restrict__ B1, const float* __restrict__ B2,
    short* __restrict__ Qp, short* __restrict__ Kp, short* __restrict__ Vp,
    float* __restrict__ outF) {
    const int z = blockIdx.z;
    const short* W  = Wb + (size_t)z * 1048576;
    const float* Bs = (z == 0) ? B0 : ((z == 1) ? B1 : B2);

    __shared__ short As[128][40];
    __shared__ short Bsh[128][40];

    const int tid  = threadIdx.x;
    const int lane = tid & 63;
    const int wv   = tid >> 6;
    const int wm   = (wv >> 1) * 64;
    const int wn   = (wv & 1) * 64;
    const int l16  = lane & 15;
    const int quad = lane >> 4;
    const int bm   = blockIdx.x * 128;
    const int bn   = blockIdx.y * 128;

    float4v zero4 = {0.f, 0.f, 0.f, 0.f};
    float4v acc[4][4];
    #pragma unroll
    for (int i = 0; i < 4; i++)
        #pragma unroll
        for (int j = 0; j < 4; j++) acc[i][j] = zero4;

    for (int kt = 0; kt < 1024; kt += 32) {
        #pragma unroll
        for (int c = tid; c < 512; c += 256) {
            int r = c >> 2, c8 = (c & 3) * 8;
            *(short8*)&As[r][c8]  = *(const short8*)(A + (size_t)(bm + r) * 1024 + kt + c8);
            *(short8*)&Bsh[r][c8] = *(const short8*)(W + (size_t)(bn + r) * 1024 + kt + c8);
        }
        __syncthreads();
        short8 af[4], bfr[4];
        #pragma unroll
        for (int mt = 0; mt < 4; mt++) af[mt]  = *(const short8*)&As[wm + mt * 16 + l16][quad * 8];
        #pragma unroll
        for (int nt = 0; nt < 4; nt++) bfr[nt] = *(const short8*)&Bsh[wn + nt * 16 + l16][quad * 8];
        #pragma unroll
        for (int mt = 0; mt < 4; mt++)
            #pragma unroll
            for (int nt = 0; nt < 4; nt++)
                acc[mt][nt] = MFMA16(af[mt], bfr[nt], acc[mt][nt]);
        __syncthreads();
    }

    #pragma unroll
    for (int mt = 0; mt < 4; mt++)
        #pragma unroll
        for (int nt = 0; nt < 4; nt++) {
            int col = bn + wn + nt * 16 + l16;
            float bias = Bs[col];
            #pragma unroll
            for (int r = 0; r < 4; r++) {
                int row = bm + wm + mt * 16 + quad * 4 + r;
                float val = acc[mt][nt][r] + bias;
                if (MODE == 1) {
                    outF[(size_t)row * 1024 + col] = val;
                } else {
                    int b = row >> 10, l = row & 1023;
                    int h = col >> 6,  d = col & 63;
                    size_t bhl = (size_t)(b * 16 + h) * 1024 + l;
                    if (z == 0)      Qp[(bhl << 7) + d] = f2bf(val * (0.125f * LOG2E));
                    else if (z == 1) Kp[(bhl << 7) + d] = f2bf(val);
                    else {
                        int slot = (l & ~31) | (((l >> 2) & 3) << 3) |
                                   (((l >> 4) & 1) << 2) | (l & 3);
                        Vp[(((size_t)(b * 16 + h) * 64 + d) << 10) + slot] = f2bf(val);
                    }
                }
            }
        }
}

// ---------------- 5) flash attention: DMA-staged K/V, static max ----------------
// grid (16 h, 8 qb, 4 b); 256 thr = 4 waves x 32 q; 64-key iterations.
// LDS tiles (double-buffered): Ks 2x[64 key][128 d] (32 KB), Vs 2x[64 d][64 slot]
// (16 KB). DMA source-side XOR swizzle: LDS 16B-block (key,dg) holds global
// dgroup dg^(key&15) (K) / block blk^(d&7) (V), so ds_read_b128 fragments are
// 2-way bank-aliased (free) while the DMA's lane-linear LDS layout is honored.
__global__ __attribute__((amdgpu_flat_work_group_size(256, 256),
                          amdgpu_waves_per_eu(2, 2)))
void flash_kernel(const short* __restrict__ Qp,
                  const short* __restrict__ Kp,
                  const short* __restrict__ Vp,
                  short* __restrict__ AO) {
    const int h  = blockIdx.x;
    const int qb = blockIdx.y;
    const int b  = blockIdx.z;
    const int tid  = threadIdx.x;
    const int lane = tid & 63;
    const int w    = tid >> 6;
    const int l16  = lane & 15;
    const int quad = lane >> 4;
    const size_t bh = (size_t)(b * 16 + h);

    __shared__ short Ks[16384];   // 2 x 8192 shorts
    __shared__ short Vs[8192];    // 2 x 4096 shorts

    // Q fragments (B-operand): lane l16 -> q row, k = quad*8 + j
    short8 qf[2][4];
    #pragma unroll
    for (int n = 0; n < 2; n++) {
        const short* Qb = Qp + ((bh * 1024 + qb * 128 + w * 32 + n * 16 + l16) << 7) + quad * 8;
        #pragma unroll
        for (int c = 0; c < 4; c++) qf[n][c] = *(const short8*)(Qb + c * 32);
    }

    // per-lane DMA source pointers (swizzle on the source side)
    const short* kSrc[4];
    #pragma unroll
    for (int jj = 0; jj < 4; jj++) {
        int key = (w * 4 + jj) * 4 + quad;
        kSrc[jj] = Kp + (bh << 17) + key * 128 + ((l16 ^ (key & 15)) * 8);
    }
    const short* vSrc[2];
    #pragma unroll
    for (int jj = 0; jj < 2; jj++) {
        int d = (w * 2 + jj) * 8 + (lane >> 3);
        vSrc[jj] = Vp + (bh << 16) + d * 1024 + (((lane & 7) ^ (d & 7)) * 8);
    }

    // LDS read bases (short idx), buf 0
    int krd[4], vrd[2];
    #pragma unroll
    for (int c = 0; c < 4; c++) krd[c] = l16 * 128 + (((c * 4 + quad) ^ l16) * 8);
    #pragma unroll
    for (int g = 0; g < 2; g++) vrd[g] = l16 * 64 + (((g * 4 + quad) ^ (l16 & 7)) * 8);

    // prologue: tile 0 -> buf 0
    #pragma unroll
    for (int jj = 0; jj < 4; jj++) dma16(kSrc[jj], &Ks[w * 2048 + jj * 512]);
    #pragma unroll
    for (int jj = 0; jj < 2; jj++) dma16(vSrc[jj], &Vs[w * 1024 + jj * 512]);
    #pragma unroll
    for (int jj = 0; jj < 4; jj++) kSrc[jj] += 8192;
    #pragma unroll
    for (int jj = 0; jj < 2; jj++) vSrc[jj] += 64;
    int dstK = 8192, dstV = 4096;

    float4v zero4 = {0.f, 0.f, 0.f, 0.f};
    float4v o_acc[4][2];
    #pragma unroll
    for (int mt = 0; mt < 4; mt++)
        #pragma unroll
        for (int n = 0; n < 2; n++) o_acc[mt][n] = zero4;
    float l_part[2] = {0.f, 0.f};

    __syncthreads();

    for (int kt = 0; kt < 16; kt++) {
        if (kt < 15) {   // DMA next tile into the other buffer
            #pragma unroll
            for (int jj = 0; jj < 4; jj++) dma16(kSrc[jj], &Ks[dstK + w * 2048 + jj * 512]);
            #pragma unroll
            for (int jj = 0; jj < 2; jj++) dma16(vSrc[jj], &Vs[dstV + w * 1024 + jj * 512]);
            #pragma unroll
            for (int jj = 0; jj < 4; jj++) kSrc[jj] += 8192;
            #pragma unroll
            for (int jj = 0; jj < 2; jj++) vSrc[jj] += 64;
            dstK ^= 8192; dstV ^= 4096;
        }

        // V^T fragments hoisted (in flight early, consumed after softmax)
        short8 vf[4][2];
        #pragma unroll
        for (int mt = 0; mt < 4; mt++)
            #pragma unroll
            for (int g = 0; g < 2; g++)
                vf[mt][g] = *(const short8*)&Vs[vrd[g] + mt * 1024];

        // S^T = K·Q^T (C-layout: col=l16=q, row=key=mt*16+quad*4+r)
        float4v s[4][2];
        #pragma unroll
        for (int mt = 0; mt < 4; mt++) {
            short8 kf[4];
            #pragma unroll
            for (int c = 0; c < 4; c++) kf[c] = *(const short8*)&Ks[krd[c] + mt * 2048];
            #pragma unroll
            for (int n = 0; n < 2; n++) {
                s[mt][n] = zero4;
                #pragma unroll
                for (int c = 0; c < 4; c++)
                    s[mt][n] = MFMA16(kf[c], qf[n][c], s[mt][n]);
            }
        }

        // p = exp2(s); per-lane partial l
        #pragma unroll
        for (int mt = 0; mt < 4; mt++)
            #pragma unroll
            for (int n = 0; n < 2; n++)
                #pragma unroll
                for (int r = 0; r < 4; r++) {
                    float p = __builtin_exp2f(s[mt][n][r]);
                    s[mt][n][r] = p;
                    l_part[n] += p;
                }

        // O^T += V^T · P^T (pf packed via v_perm)
        #pragma unroll
        for (int g = 0; g < 2; g++) {
            short8 pf[2];
            #pragma unroll
            for (int n = 0; n < 2; n++) {
                union { unsigned u[4]; short8 v; } t;
                t.u[0] = pack2bf(s[2 * g][n][0], s[2 * g][n][1]);
                t.u[1] = pack2bf(s[2 * g][n][2], s[2 * g][n][3]);
                t.u[2] = pack2bf(s[2 * g + 1][n][0], s[2 * g + 1][n][1]);
                t.u[3] = pack2bf(s[2 * g + 1][n][2], s[2 * g + 1][n][3]);
                pf[n] = t.v;
            }
            #pragma unroll
            for (int mt = 0; mt < 4; mt++)
                #pragma unroll
                for (int n = 0; n < 2; n++)
                    o_acc[mt][n] = MFMA16(vf[mt][g], pf[n], o_acc[mt][n]);
        }

        if (kt < 15) __syncthreads();   // drain DMA; protect buffer reuse
        #pragma unroll
        for (int c = 0; c < 4; c++) krd[c] ^= 8192;
        #pragma unroll
        for (int g = 0; g < 2; g++) vrd[g] ^= 4096;
    }

    // epilogue: reduce l across quads, normalize, store
    #pragma unroll
    for (int n = 0; n < 2; n++) {
        float l = l_part[n];
        l += __shfl_xor(l, 16, 64);
        l += __shfl_xor(l, 32, 64);
        float inv = 1.0f / l;
        int row = b * 1024 + qb * 128 + w * 32 + n * 16 + l16;
        #pragma unroll
        for (int mt = 0; mt < 4; mt++) {
            short4v ov;
            #pragma unroll
            for (int r = 0; r < 4; r++) ov[r] = f2bf(o_acc[mt][n][r] * inv);
            *(short4v*)(AO + (size_t)row * 1024 + h * 64 + mt * 16 + quad * 4) = ov;
        }
    }
}

extern "C" void kernel_launch(void* const* d_in, const int* in_sizes, int n_in,
                              void* d_out, int out_size, void* d_ws, size_t ws_size,
                              hipStream_t stream) {
    const float* x    = (const float*)d_in[0];
    const float* harm = (const float*)d_in[1];
    const float* wq   = (const float*)d_in[2];
    const float* bq   = (const float*)d_in[3];
    const float* wk   = (const float*)d_in[4];
    const float* bk   = (const float*)d_in[5];
    const float* wv   = (const float*)d_in[6];
    const float* bv   = (const float*)d_in[7];
    const float* wo   = (const float*)d_in[8];
    const float* bo   = (const float*)d_in[9];
    float* outF = (float*)d_out;

    short* xb   = (short*)d_ws;
    short* Qp   = xb + (size_t)4 * 1048576;
    short* Kp   = Qp + (size_t)8 * 1048576;
    short* Vp   = Kp + (size_t)8 * 1048576;
    short* Wqkv = Vp + (size_t)4 * 1048576;
    short* Wob  = Wqkv + (size_t)3 * 1048576;
    float* gram = (float*)(Wob + 1048576);
    short* AO   = xb;   // alias: xb consumed by QKV GEMM before flash writes AO

    convert_bf16<<<dim3(1024), dim3(256), 0, stream>>>(x, xb, 1048576);
    convert_w4<<<dim3(256, 4), dim3(256), 0, stream>>>(wq, wk, wv, wo, Wqkv);
    gram_kernel<<<dim3(4), dim3(256), 0, stream>>>(harm, gram);
    gemm_kernel<0><<<dim3(32, 8, 3), dim3(256), 0, stream>>>(
        xb, Wqkv, bq, bk, bv, Qp, Kp, Vp, nullptr);
    fill_aug<<<dim3(32, 4), dim3(256), 0, stream>>>(gram, Qp, Kp);
    flash_kernel<<<dim3(16, 8, 4), dim3(256), 0, stream>>>(Qp, Kp, Vp, AO);
    gemm_kernel<1><<<dim3(32, 8, 1), dim3(256), 0, stream>>>(
        AO, Wob, bo, nullptr, nullptr, nullptr, nullptr, nullptr, outF);
}

// Round 7
// 198.301 us; speedup vs baseline: 1.3784x; 1.0953x over previous
//
#include <hip/hip_runtime.h>

// ManifoldAttentionLayer on MI355X — round 6
// R5 post-mortem: flash fixed (out of top-5); GEMM now the bottleneck at
// 500 TF = exactly the m93 manual-staging plateau (MfmaUtil 18%, VALU 10%,
// 6.3e6 LDS conflicts). R6: the m97 ladder step — global_load_lds(16B)
// staging of A+W tiles (16KB LDS, lane-linear, XOR group swizzle applied on
// the DMA *source* side so ds_read_b128 fragments read contiguous 1KB spans),
// single-buffer 2-barrier K-loop. Also: gram folded into fill_aug (launch
// removed), convert kernels merged.

using short8  = __attribute__((ext_vector_type(8))) short;
using short4v = __attribute__((ext_vector_type(4))) short;
using float4v = __attribute__((ext_vector_type(4))) float;

#define MFMA16(a, b, c) __builtin_amdgcn_mfma_f32_16x16x32_bf16((a), (b), (c), 0, 0, 0)

#define LOG2E 1.44269504088896f

static __device__ __forceinline__ short f2bf(float f) {
    union { float f; unsigned u; } v; v.f = f;
    unsigned r = v.u + 0x7fffu + ((v.u >> 16) & 1u);   // round-to-nearest-even
    return (short)(r >> 16);
}

// pack two f32 -> packed bf16 pair (round-half-up): 2 adds + 1 v_perm.
static __device__ __forceinline__ unsigned pack2bf(float lo, float hi) {
    union { float f; unsigned u; } a, b;
    a.f = lo; b.f = hi;
    return __builtin_amdgcn_perm(b.u + 0x8000u, a.u + 0x8000u, 0x07060302u);
}

// async global->LDS DMA, 16B/lane; LDS dest = wave-uniform base + lane*16.
static __device__ __forceinline__ void dma16(const short* g, short* l) {
    __builtin_amdgcn_global_load_lds((const __attribute__((address_space(1))) void*)g,
                                     (__attribute__((address_space(3))) void*)l, 16, 0, 0);
}

// ---------------- 1) fp32 -> bf16: x and the 4 weight matrices ----------------
// flat chunk space: [0,1M) x -> xb ; [1M,2M) wq|wk|wv|wo -> wb (contiguous)
__global__ __launch_bounds__(256) void convert_all(
    const float* __restrict__ x,  const float* __restrict__ wq,
    const float* __restrict__ wk, const float* __restrict__ wv,
    const float* __restrict__ wo, short* __restrict__ xb, short* __restrict__ wb) {
    int idx = blockIdx.x * 256 + threadIdx.x;
    for (int i = idx; i < 2097152; i += gridDim.x * 256) {
        const float* src; short* dst;
        if (i < 1048576) {
            src = x + (size_t)i * 4;
            dst = xb + (size_t)i * 4;
        } else {
            int j = i - 1048576;
            int sel = j >> 18;
            const float* w = (sel == 0) ? wq : (sel == 1) ? wk : (sel == 2) ? wv : wo;
            src = w + (size_t)(j & 262143) * 4;
            dst = wb + (size_t)j * 4;
        }
        float4v v = *(const float4v*)src;
        short4v o;
        o.x = f2bf(v.x); o.y = f2bf(v.y); o.z = f2bf(v.z); o.w = f2bf(v.w);
        *(short4v*)dst = o;
    }
}

// ---------------- 2+4) fill augmented dims of Q'/K' (gram computed inline) ----------------
__global__ __launch_bounds__(256) void fill_aug(const float* __restrict__ harm,
                                                short* __restrict__ Qp,
                                                short* __restrict__ Kp) {
    int b  = blockIdx.y;
    int lc = blockIdx.x;
    int tid = threadIdx.x;
    int ll = tid >> 3;
    int d8 = (tid & 7) * 8;
    int l  = lc * 32 + ll;

    __shared__ float hs[64][33];
    for (int i = tid; i < 2048; i += 256) hs[i >> 5][i & 31] = harm[(size_t)b * 2048 + i];
    __syncthreads();

    float src = (l + 0.5f) * 0.0625f - 0.5f;
    if (src < 0.f) src = 0.f;
    int r0 = (int)floorf(src); if (r0 > 63) r0 = 63;
    int r1 = r0 + 1;           if (r1 > 63) r1 = 63;
    float wy = src - (float)r0;

    // interpolated harmonics row, then 8 gram dots
    float hr[32];
    #pragma unroll
    for (int k = 0; k < 32; k++) hr[k] = (1.f - wy) * hs[r0][k] + wy * hs[r1][k];

    short8 qa, ka;
    #pragma unroll
    for (int j = 0; j < 8; j++) {
        float g = 0.f;
        #pragma unroll
        for (int k = 0; k < 32; k++) g += hr[k] * hs[d8 + j][k];
        qa[j] = f2bf(0.1f * LOG2E * g);
    }
    #pragma unroll
    for (int j = 0; j < 8; j++) {
        float vv = 0.f;
        if (d8 + j == r0) vv += 1.f - wy;
        if (d8 + j == r1) vv += wy;
        ka[j] = f2bf(vv);
    }
    for (int h = 0; h < 16; h++) {
        size_t base = (((size_t)(b * 16 + h) * 1024 + l) << 7) + 64 + d8;
        *(short8*)(Qp + base) = qa;
        *(short8*)(Kp + base) = ka;
    }
}

// ---------------- 3/6) GEMM: C[4096,1024] = A(bf16) @ Wb(bf16,[N][K])^T + bias ----------------
// m97 structure: global_load_lds(16B) staging, lane-linear LDS, source-side
// XOR group swizzle (16B group gs = g^(r&3)), ds_read_b128 fragments,
// single-buffer 2-barrier K-loop.
// MODE 0: z picks q/k/v (bf16 split-head layouts; V transposed+slot-permuted).
// MODE 1: fp32 out.
template <int MODE>
__global__ __launch_bounds__(256, 2) void gemm_kernel(
    const short* __restrict__ A,
    const short* __restrict__ Wb,
    const float* __restrict__ B0, const float* __restrict__ B1, const float* __restrict__ B2,
    short* __restrict__ Qp, short* __restrict__ Kp, short* __restrict__ Vp,
    float* __restrict__ outF) {
    const int z = blockIdx.z;
    const short* W  = Wb + (size_t)z * 1048576;
    const float* Bs = (z == 0) ? B0 : ((z == 1) ? B1 : B2);

    __shared__ short Sm[8192];   // A tile [0,4096), W tile [4096,8192); 16 KB

    const int tid  = threadIdx.x;
    const int lane = tid & 63;
    const int wv   = tid >> 6;
    const int wm   = (wv >> 1) * 64;
    const int wn   = (wv & 1) * 64;
    const int l16  = lane & 15;
    const int quad = lane >> 4;
    const int bm   = blockIdx.x * 128;
    const int bn   = blockIdx.y * 128;

    // DMA source pointers: chunk c = j*256 + tid -> row r=c>>2, LDS slot g=c&3
    // holds global 16B-group gs = g ^ (r&3).
    const short* aSrc[2];
    const short* wSrc[2];
    #pragma unroll
    for (int j = 0; j < 2; j++) {
        int c = j * 256 + tid;
        int r = c >> 2, gs = (c & 3) ^ (r & 3);
        aSrc[j] = A + (size_t)(bm + r) * 1024 + gs * 8;
        wSrc[j] = W + (size_t)(bn + r) * 1024 + gs * 8;
    }
    // fragment read offsets: row rr, global group quad lives at slot quad^(rr&3);
    // rr&3 == l16&3 for all tiles.
    const int fr = ((quad ^ (l16 & 3)) * 8);
    int ai[4], bi[4];
    #pragma unroll
    for (int t = 0; t < 4; t++) {
        ai[t] = (wm + t * 16 + l16) * 32 + fr;
        bi[t] = 4096 + (wn + t * 16 + l16) * 32 + fr;
    }

    float4v zero4 = {0.f, 0.f, 0.f, 0.f};
    float4v acc[4][4];
    #pragma unroll
    for (int i = 0; i < 4; i++)
        #pragma unroll
        for (int j = 0; j < 4; j++) acc[i][j] = zero4;

    for (int kt = 0; kt < 32; kt++) {
        dma16(aSrc[0], &Sm[wv * 512]);
        dma16(aSrc[1], &Sm[2048 + wv * 512]);
        dma16(wSrc[0], &Sm[4096 + wv * 512]);
        dma16(wSrc[1], &Sm[6144 + wv * 512]);
        #pragma unroll
        for (int j = 0; j < 2; j++) { aSrc[j] += 32; wSrc[j] += 32; }
        __syncthreads();   // vmcnt(0) drain: DMA complete for all waves

        short8 af[4], bfr[4];
        #pragma unroll
        for (int mt = 0; mt < 4; mt++) af[mt]  = *(const short8*)&Sm[ai[mt]];
        #pragma unroll
        for (int nt = 0; nt < 4; nt++) bfr[nt] = *(const short8*)&Sm[bi[nt]];
        #pragma unroll
        for (int mt = 0; mt < 4; mt++)
            #pragma unroll
            for (int nt = 0; nt < 4; nt++)
                acc[mt][nt] = MFMA16(af[mt], bfr[nt], acc[mt][nt]);
        __syncthreads();   // protect single buffer before next DMA
    }

    #pragma unroll
    for (int mt = 0; mt < 4; mt++)
        #pragma unroll
        for (int nt = 0; nt < 4; nt++) {
            int col = bn + wn + nt * 16 + l16;
            float bias = Bs[col];
            #pragma unroll
            for (int r = 0; r < 4; r++) {
                int row = bm + wm + mt * 16 + quad * 4 + r;
                float val = acc[mt][nt][r] + bias;
                if (MODE == 1) {
                    outF[(size_t)row * 1024 + col] = val;
                } else {
                    int b = row >> 10, l = row & 1023;
                    int h = col >> 6,  d = col & 63;
                    size_t bhl = (size_t)(b * 16 + h) * 1024 + l;
                    if (z == 0)      Qp[(bhl << 7) + d] = f2bf(val * (0.125f * LOG2E));
                    else if (z == 1) Kp[(bhl << 7) + d] = f2bf(val);
                    else {
                        int slot = (l & ~31) | (((l >> 2) & 3) << 3) |
                                   (((l >> 4) & 1) << 2) | (l & 3);
                        Vp[(((size_t)(b * 16 + h) * 64 + d) << 10) + slot] = f2bf(val);
                    }
                }
            }
        }
}

// ---------------- 5) flash attention: DMA-staged K/V, static max (R5, unchanged) ----------------
__global__ __attribute__((amdgpu_flat_work_group_size(256, 256),
                          amdgpu_waves_per_eu(2, 2)))
void flash_kernel(const short* __restrict__ Qp,
                  const short* __restrict__ Kp,
                  const short* __restrict__ Vp,
                  short* __restrict__ AO) {
    const int h  = blockIdx.x;
    const int qb = blockIdx.y;
    const int b  = blockIdx.z;
    const int tid  = threadIdx.x;
    const int lane = tid & 63;
    const int w    = tid >> 6;
    const int l16  = lane & 15;
    const int quad = lane >> 4;
    const size_t bh = (size_t)(b * 16 + h);

    __shared__ short Ks[16384];   // 2 x 8192 shorts
    __shared__ short Vs[8192];    // 2 x 4096 shorts

    short8 qf[2][4];
    #pragma unroll
    for (int n = 0; n < 2; n++) {
        const short* Qb = Qp + ((bh * 1024 + qb * 128 + w * 32 + n * 16 + l16) << 7) + quad * 8;
        #pragma unroll
        for (int c = 0; c < 4; c++) qf[n][c] = *(const short8*)(Qb + c * 32);
    }

    const short* kSrc[4];
    #pragma unroll
    for (int jj = 0; jj < 4; jj++) {
        int key = (w * 4 + jj) * 4 + quad;
        kSrc[jj] = Kp + (bh << 17) + key * 128 + ((l16 ^ (key & 15)) * 8);
    }
    const short* vSrc[2];
    #pragma unroll
    for (int jj = 0; jj < 2; jj++) {
        int d = (w * 2 + jj) * 8 + (lane >> 3);
        vSrc[jj] = Vp + (bh << 16) + d * 1024 + (((lane & 7) ^ (d & 7)) * 8);
    }

    int krd[4], vrd[2];
    #pragma unroll
    for (int c = 0; c < 4; c++) krd[c] = l16 * 128 + (((c * 4 + quad) ^ l16) * 8);
    #pragma unroll
    for (int g = 0; g < 2; g++) vrd[g] = l16 * 64 + (((g * 4 + quad) ^ (l16 & 7)) * 8);

    #pragma unroll
    for (int jj = 0; jj < 4; jj++) dma16(kSrc[jj], &Ks[w * 2048 + jj * 512]);
    #pragma unroll
    for (int jj = 0; jj < 2; jj++) dma16(vSrc[jj], &Vs[w * 1024 + jj * 512]);
    #pragma unroll
    for (int jj = 0; jj < 4; jj++) kSrc[jj] += 8192;
    #pragma unroll
    for (int jj = 0; jj < 2; jj++) vSrc[jj] += 64;
    int dstK = 8192, dstV = 4096;

    float4v zero4 = {0.f, 0.f, 0.f, 0.f};
    float4v o_acc[4][2];
    #pragma unroll
    for (int mt = 0; mt < 4; mt++)
        #pragma unroll
        for (int n = 0; n < 2; n++) o_acc[mt][n] = zero4;
    float l_part[2] = {0.f, 0.f};

    __syncthreads();

    for (int kt = 0; kt < 16; kt++) {
        if (kt < 15) {
            #pragma unroll
            for (int jj = 0; jj < 4; jj++) dma16(kSrc[jj], &Ks[dstK + w * 2048 + jj * 512]);
            #pragma unroll
            for (int jj = 0; jj < 2; jj++) dma16(vSrc[jj], &Vs[dstV + w * 1024 + jj * 512]);
            #pragma unroll
            for (int jj = 0; jj < 4; jj++) kSrc[jj] += 8192;
            #pragma unroll
            for (int jj = 0; jj < 2; jj++) vSrc[jj] += 64;
            dstK ^= 8192; dstV ^= 4096;
        }

        short8 vf[4][2];
        #pragma unroll
        for (int mt = 0; mt < 4; mt++)
            #pragma unroll
            for (int g = 0; g < 2; g++)
                vf[mt][g] = *(const short8*)&Vs[vrd[g] + mt * 1024];

        float4v s[4][2];
        #pragma unroll
        for (int mt = 0; mt < 4; mt++) {
            short8 kf[4];
            #pragma unroll
            for (int c = 0; c < 4; c++) kf[c] = *(const short8*)&Ks[krd[c] + mt * 2048];
            #pragma unroll
            for (int n = 0; n < 2; n++) {
                s[mt][n] = zero4;
                #pragma unroll
                for (int c = 0; c < 4; c++)
                    s[mt][n] = MFMA16(kf[c], qf[n][c], s[mt][n]);
            }
        }

        #pragma unroll
        for (int mt = 0; mt < 4; mt++)
            #pragma unroll
            for (int n = 0; n < 2; n++)
                #pragma unroll
                for (int r = 0; r < 4; r++) {
                    float p = __builtin_exp2f(s[mt][n][r]);
                    s[mt][n][r] = p;
                    l_part[n] += p;
                }

        #pragma unroll
        for (int g = 0; g < 2; g++) {
            short8 pf[2];
            #pragma unroll
            for (int n = 0; n < 2; n++) {
                union { unsigned u[4]; short8 v; } t;
                t.u[0] = pack2bf(s[2 * g][n][0], s[2 * g][n][1]);
                t.u[1] = pack2bf(s[2 * g][n][2], s[2 * g][n][3]);
                t.u[2] = pack2bf(s[2 * g + 1][n][0], s[2 * g + 1][n][1]);
                t.u[3] = pack2bf(s[2 * g + 1][n][2], s[2 * g + 1][n][3]);
                pf[n] = t.v;
            }
            #pragma unroll
            for (int mt = 0; mt < 4; mt++)
                #pragma unroll
                for (int n = 0; n < 2; n++)
                    o_acc[mt][n] = MFMA16(vf[mt][g], pf[n], o_acc[mt][n]);
        }

        if (kt < 15) __syncthreads();
        #pragma unroll
        for (int c = 0; c < 4; c++) krd[c] ^= 8192;
        #pragma unroll
        for (int g = 0; g < 2; g++) vrd[g] ^= 4096;
    }

    #pragma unroll
    for (int n = 0; n < 2; n++) {
        float l = l_part[n];
        l += __shfl_xor(l, 16, 64);
        l += __shfl_xor(l, 32, 64);
        float inv = 1.0f / l;
        int row = b * 1024 + qb * 128 + w * 32 + n * 16 + l16;
        #pragma unroll
        for (int mt = 0; mt < 4; mt++) {
            short4v ov;
            #pragma unroll
            for (int r = 0; r < 4; r++) ov[r] = f2bf(o_acc[mt][n][r] * inv);
            *(short4v*)(AO + (size_t)row * 1024 + h * 64 + mt * 16 + quad * 4) = ov;
        }
    }
}

extern "C" void kernel_launch(void* const* d_in, const int* in_sizes, int n_in,
                              void* d_out, int out_size, void* d_ws, size_t ws_size,
                              hipStream_t stream) {
    const float* x    = (const float*)d_in[0];
    const float* harm = (const float*)d_in[1];
    const float* wq   = (const float*)d_in[2];
    const float* bq   = (const float*)d_in[3];
    const float* wk   = (const float*)d_in[4];
    const float* bk   = (const float*)d_in[5];
    const float* wv   = (const float*)d_in[6];
    const float* bv   = (const float*)d_in[7];
    const float* wo   = (const float*)d_in[8];
    const float* bo   = (const float*)d_in[9];
    float* outF = (float*)d_out;

    short* xb   = (short*)d_ws;                 // 4M shorts; ALIASED as AO
    short* Qp   = xb + (size_t)4 * 1048576;     // 8M shorts
    short* Kp   = Qp + (size_t)8 * 1048576;     // 8M shorts
    short* Vp   = Kp + (size_t)8 * 1048576;     // 4M shorts
    short* Wqkv = Vp + (size_t)4 * 1048576;     // 3M shorts (wq,wk,wv)
    short* Wob  = Wqkv + (size_t)3 * 1048576;   // 1M shorts (wo) — contiguous after Wqkv
    short* AO   = xb;   // alias: xb consumed by QKV GEMM before flash writes AO

    convert_all<<<dim3(2048), dim3(256), 0, stream>>>(x, wq, wk, wv, wo, xb, Wqkv);
    gemm_kernel<0><<<dim3(32, 8, 3), dim3(256), 0, stream>>>(
        xb, Wqkv, bq, bk, bv, Qp, Kp, Vp, nullptr);
    fill_aug<<<dim3(32, 4), dim3(256), 0, stream>>>(harm, Qp, Kp);
    flash_kernel<<<dim3(16, 8, 4), dim3(256), 0, stream>>>(Qp, Kp, Vp, AO);
    gemm_kernel<1><<<dim3(32, 8, 1), dim3(256), 0, stream>>>(
        AO, Wob, bo, nullptr, nullptr, nullptr, nullptr, nullptr, outF);
}

// Round 8
// 194.543 us; speedup vs baseline: 1.4050x; 1.0193x over previous
//
#include <hip/hip_runtime.h>

// ManifoldAttentionLayer on MI355X — round 7
// R6 post-mortem: (a) gemm swizzle keyed on r&3 but LDS bank pattern has
// period 2 rows (64B rows) -> half the banks idle on reads, 3.1e6 conflicts
// remained; fix: (r>>1)&3. (b) single-buffer 2-barrier K-loop exposes the
// full DMA drain (issue -> immediate vmcnt(0) barrier, no compute between);
// at 1-1.5 resident blocks/CU there is no inter-block overlap to absorb it.
// R7: double-buffered LDS (2x16KB), DMA(k+1) issued BEFORE compute(k), one
// barrier/iter (the proven R5-flash staging discipline), corrected swizzle.

using short8  = __attribute__((ext_vector_type(8))) short;
using short4v = __attribute__((ext_vector_type(4))) short;
using float4v = __attribute__((ext_vector_type(4))) float;

#define MFMA16(a, b, c) __builtin_amdgcn_mfma_f32_16x16x32_bf16((a), (b), (c), 0, 0, 0)

#define LOG2E 1.44269504088896f

static __device__ __forceinline__ short f2bf(float f) {
    union { float f; unsigned u; } v; v.f = f;
    unsigned r = v.u + 0x7fffu + ((v.u >> 16) & 1u);   // round-to-nearest-even
    return (short)(r >> 16);
}

// pack two f32 -> packed bf16 pair (round-half-up): 2 adds + 1 v_perm.
static __device__ __forceinline__ unsigned pack2bf(float lo, float hi) {
    union { float f; unsigned u; } a, b;
    a.f = lo; b.f = hi;
    return __builtin_amdgcn_perm(b.u + 0x8000u, a.u + 0x8000u, 0x07060302u);
}

// async global->LDS DMA, 16B/lane; LDS dest = wave-uniform base + lane*16.
static __device__ __forceinline__ void dma16(const short* g, short* l) {
    __builtin_amdgcn_global_load_lds((const __attribute__((address_space(1))) void*)g,
                                     (__attribute__((address_space(3))) void*)l, 16, 0, 0);
}

// ---------------- 1) fp32 -> bf16: x and the 4 weight matrices ----------------
__global__ __launch_bounds__(256) void convert_all(
    const float* __restrict__ x,  const float* __restrict__ wq,
    const float* __restrict__ wk, const float* __restrict__ wv,
    const float* __restrict__ wo, short* __restrict__ xb, short* __restrict__ wb) {
    int idx = blockIdx.x * 256 + threadIdx.x;
    for (int i = idx; i < 2097152; i += gridDim.x * 256) {
        const float* src; short* dst;
        if (i < 1048576) {
            src = x + (size_t)i * 4;
            dst = xb + (size_t)i * 4;
        } else {
            int j = i - 1048576;
            int sel = j >> 18;
            const float* w = (sel == 0) ? wq : (sel == 1) ? wk : (sel == 2) ? wv : wo;
            src = w + (size_t)(j & 262143) * 4;
            dst = wb + (size_t)j * 4;
        }
        float4v v = *(const float4v*)src;
        short4v o;
        o.x = f2bf(v.x); o.y = f2bf(v.y); o.z = f2bf(v.z); o.w = f2bf(v.w);
        *(short4v*)dst = o;
    }
}

// ---------------- 2+4) fill augmented dims of Q'/K' (gram inline) ----------------
__global__ __launch_bounds__(256) void fill_aug(const float* __restrict__ harm,
                                                short* __restrict__ Qp,
                                                short* __restrict__ Kp) {
    int b  = blockIdx.y;
    int lc = blockIdx.x;
    int tid = threadIdx.x;
    int ll = tid >> 3;
    int d8 = (tid & 7) * 8;
    int l  = lc * 32 + ll;

    __shared__ float hs[64][33];
    for (int i = tid; i < 2048; i += 256) hs[i >> 5][i & 31] = harm[(size_t)b * 2048 + i];
    __syncthreads();

    float src = (l + 0.5f) * 0.0625f - 0.5f;
    if (src < 0.f) src = 0.f;
    int r0 = (int)floorf(src); if (r0 > 63) r0 = 63;
    int r1 = r0 + 1;           if (r1 > 63) r1 = 63;
    float wy = src - (float)r0;

    float hr[32];
    #pragma unroll
    for (int k = 0; k < 32; k++) hr[k] = (1.f - wy) * hs[r0][k] + wy * hs[r1][k];

    short8 qa, ka;
    #pragma unroll
    for (int j = 0; j < 8; j++) {
        float g = 0.f;
        #pragma unroll
        for (int k = 0; k < 32; k++) g += hr[k] * hs[d8 + j][k];
        qa[j] = f2bf(0.1f * LOG2E * g);
    }
    #pragma unroll
    for (int j = 0; j < 8; j++) {
        float vv = 0.f;
        if (d8 + j == r0) vv += 1.f - wy;
        if (d8 + j == r1) vv += wy;
        ka[j] = f2bf(vv);
    }
    for (int h = 0; h < 16; h++) {
        size_t base = (((size_t)(b * 16 + h) * 1024 + l) << 7) + 64 + d8;
        *(short8*)(Qp + base) = qa;
        *(short8*)(Kp + base) = ka;
    }
}

// ---------------- 3/6) GEMM: C[4096,1024] = A(bf16) @ Wb(bf16,[N][K])^T + bias ----------------
// Double-buffered DMA staging; source-side XOR swizzle keyed (r>>1)&3 so
// ds_read_b128 fragments hit the 8-dword/bank structural minimum.
template <int MODE>
__global__ __launch_bounds__(256, 2) void gemm_kernel(
    const short* __restrict__ A,
    const short* __restrict__ Wb,
    const float* __restrict__ B0, const float* __restrict__ B1, const float* __restrict__ B2,
    short* __restrict__ Qp, short* __restrict__ Kp, short* __restrict__ Vp,
    float* __restrict__ outF) {
    const int z = blockIdx.z;
    const short* W  = Wb + (size_t)z * 1048576;
    const float* Bs = (z == 0) ? B0 : ((z == 1) ? B1 : B2);

    __shared__ short Sm[2][8192];   // [buf][A 0..4096 | W 4096..8192], 32 KB

    const int tid  = threadIdx.x;
    const int lane = tid & 63;
    const int wv   = tid >> 6;
    const int wm   = (wv >> 1) * 64;
    const int wn   = (wv & 1) * 64;
    const int l16  = lane & 15;
    const int quad = lane >> 4;
    const int bm   = blockIdx.x * 128;
    const int bn   = blockIdx.y * 128;

    // DMA sources: chunk c = j*256+tid -> row r=c>>2, LDS slot g=c&3 holds
    // global 16B-group gs = g ^ ((r>>1)&3)  (bank period = 2 rows).
    const short* aSrc[2];
    const short* wSrc[2];
    #pragma unroll
    for (int j = 0; j < 2; j++) {
        int c = j * 256 + tid;
        int r = c >> 2, gs = (c & 3) ^ ((r >> 1) & 3);
        aSrc[j] = A + (size_t)(bm + r) * 1024 + gs * 8;
        wSrc[j] = W + (size_t)(bn + r) * 1024 + gs * 8;
    }
    // fragment reads: global group quad of row rr lives at slot quad^((rr>>1)&3);
    // (rr>>1)&3 == (l16>>1)&3 for all tile rows (wm/wn/t*16 are multiples of 16).
    const int fr = (quad ^ ((l16 >> 1) & 3)) * 8;
    int ai[4], bi[4];
    #pragma unroll
    for (int t = 0; t < 4; t++) {
        ai[t] = (wm + t * 16 + l16) * 32 + fr;
        bi[t] = 4096 + (wn + t * 16 + l16) * 32 + fr;
    }

    float4v zero4 = {0.f, 0.f, 0.f, 0.f};
    float4v acc[4][4];
    #pragma unroll
    for (int i = 0; i < 4; i++)
        #pragma unroll
        for (int j = 0; j < 4; j++) acc[i][j] = zero4;

    // prologue: tile 0 -> buf 0
    dma16(aSrc[0], &Sm[0][wv * 512]);
    dma16(aSrc[1], &Sm[0][2048 + wv * 512]);
    dma16(wSrc[0], &Sm[0][4096 + wv * 512]);
    dma16(wSrc[1], &Sm[0][6144 + wv * 512]);
    #pragma unroll
    for (int j = 0; j < 2; j++) { aSrc[j] += 32; wSrc[j] += 32; }
    __syncthreads();

    for (int kt = 0; kt < 32; kt++) {
        const int cur = kt & 1, nxt = cur ^ 1;
        if (kt < 31) {   // DMA next tile; latency hidden behind this iter's MFMA
            dma16(aSrc[0], &Sm[nxt][wv * 512]);
            dma16(aSrc[1], &Sm[nxt][2048 + wv * 512]);
            dma16(wSrc[0], &Sm[nxt][4096 + wv * 512]);
            dma16(wSrc[1], &Sm[nxt][6144 + wv * 512]);
            #pragma unroll
            for (int j = 0; j < 2; j++) { aSrc[j] += 32; wSrc[j] += 32; }
        }

        short8 af[4], bfr[4];
        #pragma unroll
        for (int mt = 0; mt < 4; mt++) af[mt]  = *(const short8*)&Sm[cur][ai[mt]];
        #pragma unroll
        for (int nt = 0; nt < 4; nt++) bfr[nt] = *(const short8*)&Sm[cur][bi[nt]];
        #pragma unroll
        for (int mt = 0; mt < 4; mt++)
            #pragma unroll
            for (int nt = 0; nt < 4; nt++)
                acc[mt][nt] = MFMA16(af[mt], bfr[nt], acc[mt][nt]);

        __syncthreads();   // one barrier/iter: drains next-DMA + protects cur buf
    }

    #pragma unroll
    for (int mt = 0; mt < 4; mt++)
        #pragma unroll
        for (int nt = 0; nt < 4; nt++) {
            int col = bn + wn + nt * 16 + l16;
            float bias = Bs[col];
            #pragma unroll
            for (int r = 0; r < 4; r++) {
                int row = bm + wm + mt * 16 + quad * 4 + r;
                float val = acc[mt][nt][r] + bias;
                if (MODE == 1) {
                    outF[(size_t)row * 1024 + col] = val;
                } else {
                    int b = row >> 10, l = row & 1023;
                    int h = col >> 6,  d = col & 63;
                    size_t bhl = (size_t)(b * 16 + h) * 1024 + l;
                    if (z == 0)      Qp[(bhl << 7) + d] = f2bf(val * (0.125f * LOG2E));
                    else if (z == 1) Kp[(bhl << 7) + d] = f2bf(val);
                    else {
                        int slot = (l & ~31) | (((l >> 2) & 3) << 3) |
                                   (((l >> 4) & 1) << 2) | (l & 3);
                        Vp[(((size_t)(b * 16 + h) * 64 + d) << 10) + slot] = f2bf(val);
                    }
                }
            }
        }
}

// ---------------- 5) flash attention: DMA-staged K/V, static max (R5, unchanged) ----------------
__global__ __attribute__((amdgpu_flat_work_group_size(256, 256),
                          amdgpu_waves_per_eu(2, 2)))
void flash_kernel(const short* __restrict__ Qp,
                  const short* __restrict__ Kp,
                  const short* __restrict__ Vp,
                  short* __restrict__ AO) {
    const int h  = blockIdx.x;
    const int qb = blockIdx.y;
    const int b  = blockIdx.z;
    const int tid  = threadIdx.x;
    const int lane = tid & 63;
    const int w    = tid >> 6;
    const int l16  = lane & 15;
    const int quad = lane >> 4;
    const size_t bh = (size_t)(b * 16 + h);

    __shared__ short Ks[16384];   // 2 x 8192 shorts
    __shared__ short Vs[8192];    // 2 x 4096 shorts

    short8 qf[2][4];
    #pragma unroll
    for (int n = 0; n < 2; n++) {
        const short* Qb = Qp + ((bh * 1024 + qb * 128 + w * 32 + n * 16 + l16) << 7) + quad * 8;
        #pragma unroll
        for (int c = 0; c < 4; c++) qf[n][c] = *(const short8*)(Qb + c * 32);
    }

    const short* kSrc[4];
    #pragma unroll
    for (int jj = 0; jj < 4; jj++) {
        int key = (w * 4 + jj) * 4 + quad;
        kSrc[jj] = Kp + (bh << 17) + key * 128 + ((l16 ^ (key & 15)) * 8);
    }
    const short* vSrc[2];
    #pragma unroll
    for (int jj = 0; jj < 2; jj++) {
        int d = (w * 2 + jj) * 8 + (lane >> 3);
        vSrc[jj] = Vp + (bh << 16) + d * 1024 + (((lane & 7) ^ (d & 7)) * 8);
    }

    int krd[4], vrd[2];
    #pragma unroll
    for (int c = 0; c < 4; c++) krd[c] = l16 * 128 + (((c * 4 + quad) ^ l16) * 8);
    #pragma unroll
    for (int g = 0; g < 2; g++) vrd[g] = l16 * 64 + (((g * 4 + quad) ^ (l16 & 7)) * 8);

    #pragma unroll
    for (int jj = 0; jj < 4; jj++) dma16(kSrc[jj], &Ks[w * 2048 + jj * 512]);
    #pragma unroll
    for (int jj = 0; jj < 2; jj++) dma16(vSrc[jj], &Vs[w * 1024 + jj * 512]);
    #pragma unroll
    for (int jj = 0; jj < 4; jj++) kSrc[jj] += 8192;
    #pragma unroll
    for (int jj = 0; jj < 2; jj++) vSrc[jj] += 64;
    int dstK = 8192, dstV = 4096;

    float4v zero4 = {0.f, 0.f, 0.f, 0.f};
    float4v o_acc[4][2];
    #pragma unroll
    for (int mt = 0; mt < 4; mt++)
        #pragma unroll
        for (int n = 0; n < 2; n++) o_acc[mt][n] = zero4;
    float l_part[2] = {0.f, 0.f};

    __syncthreads();

    for (int kt = 0; kt < 16; kt++) {
        if (kt < 15) {
            #pragma unroll
            for (int jj = 0; jj < 4; jj++) dma16(kSrc[jj], &Ks[dstK + w * 2048 + jj * 512]);
            #pragma unroll
            for (int jj = 0; jj < 2; jj++) dma16(vSrc[jj], &Vs[dstV + w * 1024 + jj * 512]);
            #pragma unroll
            for (int jj = 0; jj < 4; jj++) kSrc[jj] += 8192;
            #pragma unroll
            for (int jj = 0; jj < 2; jj++) vSrc[jj] += 64;
            dstK ^= 8192; dstV ^= 4096;
        }

        short8 vf[4][2];
        #pragma unroll
        for (int mt = 0; mt < 4; mt++)
            #pragma unroll
            for (int g = 0; g < 2; g++)
                vf[mt][g] = *(const short8*)&Vs[vrd[g] + mt * 1024];

        float4v s[4][2];
        #pragma unroll
        for (int mt = 0; mt < 4; mt++) {
            short8 kf[4];
            #pragma unroll
            for (int c = 0; c < 4; c++) kf[c] = *(const short8*)&Ks[krd[c] + mt * 2048];
            #pragma unroll
            for (int n = 0; n < 2; n++) {
                s[mt][n] = zero4;
                #pragma unroll
                for (int c = 0; c < 4; c++)
                    s[mt][n] = MFMA16(kf[c], qf[n][c], s[mt][n]);
            }
        }

        #pragma unroll
        for (int mt = 0; mt < 4; mt++)
            #pragma unroll
            for (int n = 0; n < 2; n++)
                #pragma unroll
                for (int r = 0; r < 4; r++) {
                    float p = __builtin_exp2f(s[mt][n][r]);
                    s[mt][n][r] = p;
                    l_part[n] += p;
                }

        #pragma unroll
        for (int g = 0; g < 2; g++) {
            short8 pf[2];
            #pragma unroll
            for (int n = 0; n < 2; n++) {
                union { unsigned u[4]; short8 v; } t;
                t.u[0] = pack2bf(s[2 * g][n][0], s[2 * g][n][1]);
                t.u[1] = pack2bf(s[2 * g][n][2], s[2 * g][n][3]);
                t.u[2] = pack2bf(s[2 * g + 1][n][0], s[2 * g + 1][n][1]);
                t.u[3] = pack2bf(s[2 * g + 1][n][2], s[2 * g + 1][n][3]);
                pf[n] = t.v;
            }
            #pragma unroll
            for (int mt = 0; mt < 4; mt++)
                #pragma unroll
                for (int n = 0; n < 2; n++)
                    o_acc[mt][n] = MFMA16(vf[mt][g], pf[n], o_acc[mt][n]);
        }

        if (kt < 15) __syncthreads();
        #pragma unroll
        for (int c = 0; c < 4; c++) krd[c] ^= 8192;
        #pragma unroll
        for (int g = 0; g < 2; g++) vrd[g] ^= 4096;
    }

    #pragma unroll
    for (int n = 0; n < 2; n++) {
        float l = l_part[n];
        l += __shfl_xor(l, 16, 64);
        l += __shfl_xor(l, 32, 64);
        float inv = 1.0f / l;
        int row = b * 1024 + qb * 128 + w * 32 + n * 16 + l16;
        #pragma unroll
        for (int mt = 0; mt < 4; mt++) {
            short4v ov;
            #pragma unroll
            for (int r = 0; r < 4; r++) ov[r] = f2bf(o_acc[mt][n][r] * inv);
            *(short4v*)(AO + (size_t)row * 1024 + h * 64 + mt * 16 + quad * 4) = ov;
        }
    }
}

extern "C" void kernel_launch(void* const* d_in, const int* in_sizes, int n_in,
                              void* d_out, int out_size, void* d_ws, size_t ws_size,
                              hipStream_t stream) {
    const float* x    = (const float*)d_in[0];
    const float* harm = (const float*)d_in[1];
    const float* wq   = (const float*)d_in[2];
    const float* bq   = (const float*)d_in[3];
    const float* wk   = (const float*)d_in[4];
    const float* bk   = (const float*)d_in[5];
    const float* wv   = (const float*)d_in[6];
    const float* bv   = (const float*)d_in[7];
    const float* wo   = (const float*)d_in[8];
    const float* bo   = (const float*)d_in[9];
    float* outF = (float*)d_out;

    short* xb   = (short*)d_ws;                 // 4M shorts; ALIASED as AO
    short* Qp   = xb + (size_t)4 * 1048576;     // 8M shorts
    short* Kp   = Qp + (size_t)8 * 1048576;     // 8M shorts
    short* Vp   = Kp + (size_t)8 * 1048576;     // 4M shorts
    short* Wqkv = Vp + (size_t)4 * 1048576;     // 3M shorts (wq,wk,wv)
    short* Wob  = Wqkv + (size_t)3 * 1048576;   // 1M shorts (wo)
    short* AO   = xb;   // alias: xb consumed by QKV GEMM before flash writes AO

    convert_all<<<dim3(2048), dim3(256), 0, stream>>>(x, wq, wk, wv, wo, xb, Wqkv);
    gemm_kernel<0><<<dim3(32, 8, 3), dim3(256), 0, stream>>>(
        xb, Wqkv, bq, bk, bv, Qp, Kp, Vp, nullptr);
    fill_aug<<<dim3(32, 4), dim3(256), 0, stream>>>(harm, Qp, Kp);
    flash_kernel<<<dim3(16, 8, 4), dim3(256), 0, stream>>>(Qp, Kp, Vp, AO);
    gemm_kernel<1><<<dim3(32, 8, 1), dim3(256), 0, stream>>>(
        AO, Wob, bo, nullptr, nullptr, nullptr, nullptr, nullptr, outF);
}

// Round 9
// 194.143 us; speedup vs baseline: 1.4079x; 1.0021x over previous
//
#include <hip/hip_runtime.h>

// ManifoldAttentionLayer on MI355X — round 8
// R7 post-mortem: gemm fixed (out of top-5); flash now the top dispatch at
// 44.3us with VALUBusy 42.7% vs MfmaUtil 21.2% at 2 waves/SIMD — the softmax
// VALU chain (32 v_exp + 32 adds + 48 pack ops per wave-iter) is the floor
// and the pipe idles waiting on the serial chain. R8: 512-thread flash blocks
// (8 waves x 16 q, same 128 q/block, same LDS/grid) -> 4 waves/SIMD so VALU
// and MFMA pipes stay fed; per-wave regs halve to fit 128-VGPR @ waves_per_eu(4,4).

using short8  = __attribute__((ext_vector_type(8))) short;
using short4v = __attribute__((ext_vector_type(4))) short;
using float4v = __attribute__((ext_vector_type(4))) float;

#define MFMA16(a, b, c) __builtin_amdgcn_mfma_f32_16x16x32_bf16((a), (b), (c), 0, 0, 0)

#define LOG2E 1.44269504088896f

static __device__ __forceinline__ short f2bf(float f) {
    union { float f; unsigned u; } v; v.f = f;
    unsigned r = v.u + 0x7fffu + ((v.u >> 16) & 1u);   // round-to-nearest-even
    return (short)(r >> 16);
}

// pack two f32 -> packed bf16 pair (round-half-up): 2 adds + 1 v_perm.
static __device__ __forceinline__ unsigned pack2bf(float lo, float hi) {
    union { float f; unsigned u; } a, b;
    a.f = lo; b.f = hi;
    return __builtin_amdgcn_perm(b.u + 0x8000u, a.u + 0x8000u, 0x07060302u);
}

// async global->LDS DMA, 16B/lane; LDS dest = wave-uniform base + lane*16.
static __device__ __forceinline__ void dma16(const short* g, short* l) {
    __builtin_amdgcn_global_load_lds((const __attribute__((address_space(1))) void*)g,
                                     (__attribute__((address_space(3))) void*)l, 16, 0, 0);
}

// ---------------- 1) fp32 -> bf16: x and the 4 weight matrices ----------------
__global__ __launch_bounds__(256) void convert_all(
    const float* __restrict__ x,  const float* __restrict__ wq,
    const float* __restrict__ wk, const float* __restrict__ wv,
    const float* __restrict__ wo, short* __restrict__ xb, short* __restrict__ wb) {
    int idx = blockIdx.x * 256 + threadIdx.x;
    for (int i = idx; i < 2097152; i += gridDim.x * 256) {
        const float* src; short* dst;
        if (i < 1048576) {
            src = x + (size_t)i * 4;
            dst = xb + (size_t)i * 4;
        } else {
            int j = i - 1048576;
            int sel = j >> 18;
            const float* w = (sel == 0) ? wq : (sel == 1) ? wk : (sel == 2) ? wv : wo;
            src = w + (size_t)(j & 262143) * 4;
            dst = wb + (size_t)j * 4;
        }
        float4v v = *(const float4v*)src;
        short4v o;
        o.x = f2bf(v.x); o.y = f2bf(v.y); o.z = f2bf(v.z); o.w = f2bf(v.w);
        *(short4v*)dst = o;
    }
}

// ---------------- 2+4) fill augmented dims of Q'/K' (gram inline) ----------------
__global__ __launch_bounds__(256) void fill_aug(const float* __restrict__ harm,
                                                short* __restrict__ Qp,
                                                short* __restrict__ Kp) {
    int b  = blockIdx.y;
    int lc = blockIdx.x;
    int tid = threadIdx.x;
    int ll = tid >> 3;
    int d8 = (tid & 7) * 8;
    int l  = lc * 32 + ll;

    __shared__ float hs[64][33];
    for (int i = tid; i < 2048; i += 256) hs[i >> 5][i & 31] = harm[(size_t)b * 2048 + i];
    __syncthreads();

    float src = (l + 0.5f) * 0.0625f - 0.5f;
    if (src < 0.f) src = 0.f;
    int r0 = (int)floorf(src); if (r0 > 63) r0 = 63;
    int r1 = r0 + 1;           if (r1 > 63) r1 = 63;
    float wy = src - (float)r0;

    float hr[32];
    #pragma unroll
    for (int k = 0; k < 32; k++) hr[k] = (1.f - wy) * hs[r0][k] + wy * hs[r1][k];

    short8 qa, ka;
    #pragma unroll
    for (int j = 0; j < 8; j++) {
        float g = 0.f;
        #pragma unroll
        for (int k = 0; k < 32; k++) g += hr[k] * hs[d8 + j][k];
        qa[j] = f2bf(0.1f * LOG2E * g);
    }
    #pragma unroll
    for (int j = 0; j < 8; j++) {
        float vv = 0.f;
        if (d8 + j == r0) vv += 1.f - wy;
        if (d8 + j == r1) vv += wy;
        ka[j] = f2bf(vv);
    }
    for (int h = 0; h < 16; h++) {
        size_t base = (((size_t)(b * 16 + h) * 1024 + l) << 7) + 64 + d8;
        *(short8*)(Qp + base) = qa;
        *(short8*)(Kp + base) = ka;
    }
}

// ---------------- 3/6) GEMM (R7 structure, unchanged) ----------------
template <int MODE>
__global__ __launch_bounds__(256, 2) void gemm_kernel(
    const short* __restrict__ A,
    const short* __restrict__ Wb,
    const float* __restrict__ B0, const float* __restrict__ B1, const float* __restrict__ B2,
    short* __restrict__ Qp, short* __restrict__ Kp, short* __restrict__ Vp,
    float* __restrict__ outF) {
    const int z = blockIdx.z;
    const short* W  = Wb + (size_t)z * 1048576;
    const float* Bs = (z == 0) ? B0 : ((z == 1) ? B1 : B2);

    __shared__ short Sm[2][8192];   // [buf][A 0..4096 | W 4096..8192], 32 KB

    const int tid  = threadIdx.x;
    const int lane = tid & 63;
    const int wv   = tid >> 6;
    const int wm   = (wv >> 1) * 64;
    const int wn   = (wv & 1) * 64;
    const int l16  = lane & 15;
    const int quad = lane >> 4;
    const int bm   = blockIdx.x * 128;
    const int bn   = blockIdx.y * 128;

    const short* aSrc[2];
    const short* wSrc[2];
    #pragma unroll
    for (int j = 0; j < 2; j++) {
        int c = j * 256 + tid;
        int r = c >> 2, gs = (c & 3) ^ ((r >> 1) & 3);
        aSrc[j] = A + (size_t)(bm + r) * 1024 + gs * 8;
        wSrc[j] = W + (size_t)(bn + r) * 1024 + gs * 8;
    }
    const int fr = (quad ^ ((l16 >> 1) & 3)) * 8;
    int ai[4], bi[4];
    #pragma unroll
    for (int t = 0; t < 4; t++) {
        ai[t] = (wm + t * 16 + l16) * 32 + fr;
        bi[t] = 4096 + (wn + t * 16 + l16) * 32 + fr;
    }

    float4v zero4 = {0.f, 0.f, 0.f, 0.f};
    float4v acc[4][4];
    #pragma unroll
    for (int i = 0; i < 4; i++)
        #pragma unroll
        for (int j = 0; j < 4; j++) acc[i][j] = zero4;

    dma16(aSrc[0], &Sm[0][wv * 512]);
    dma16(aSrc[1], &Sm[0][2048 + wv * 512]);
    dma16(wSrc[0], &Sm[0][4096 + wv * 512]);
    dma16(wSrc[1], &Sm[0][6144 + wv * 512]);
    #pragma unroll
    for (int j = 0; j < 2; j++) { aSrc[j] += 32; wSrc[j] += 32; }
    __syncthreads();

    for (int kt = 0; kt < 32; kt++) {
        const int cur = kt & 1, nxt = cur ^ 1;
        if (kt < 31) {
            dma16(aSrc[0], &Sm[nxt][wv * 512]);
            dma16(aSrc[1], &Sm[nxt][2048 + wv * 512]);
            dma16(wSrc[0], &Sm[nxt][4096 + wv * 512]);
            dma16(wSrc[1], &Sm[nxt][6144 + wv * 512]);
            #pragma unroll
            for (int j = 0; j < 2; j++) { aSrc[j] += 32; wSrc[j] += 32; }
        }

        short8 af[4], bfr[4];
        #pragma unroll
        for (int mt = 0; mt < 4; mt++) af[mt]  = *(const short8*)&Sm[cur][ai[mt]];
        #pragma unroll
        for (int nt = 0; nt < 4; nt++) bfr[nt] = *(const short8*)&Sm[cur][bi[nt]];
        #pragma unroll
        for (int mt = 0; mt < 4; mt++)
            #pragma unroll
            for (int nt = 0; nt < 4; nt++)
                acc[mt][nt] = MFMA16(af[mt], bfr[nt], acc[mt][nt]);

        __syncthreads();
    }

    #pragma unroll
    for (int mt = 0; mt < 4; mt++)
        #pragma unroll
        for (int nt = 0; nt < 4; nt++) {
            int col = bn + wn + nt * 16 + l16;
            float bias = Bs[col];
            #pragma unroll
            for (int r = 0; r < 4; r++) {
                int row = bm + wm + mt * 16 + quad * 4 + r;
                float val = acc[mt][nt][r] + bias;
                if (MODE == 1) {
                    outF[(size_t)row * 1024 + col] = val;
                } else {
                    int b = row >> 10, l = row & 1023;
                    int h = col >> 6,  d = col & 63;
                    size_t bhl = (size_t)(b * 16 + h) * 1024 + l;
                    if (z == 0)      Qp[(bhl << 7) + d] = f2bf(val * (0.125f * LOG2E));
                    else if (z == 1) Kp[(bhl << 7) + d] = f2bf(val);
                    else {
                        int slot = (l & ~31) | (((l >> 2) & 3) << 3) |
                                   (((l >> 4) & 1) << 2) | (l & 3);
                        Vp[(((size_t)(b * 16 + h) * 64 + d) << 10) + slot] = f2bf(val);
                    }
                }
            }
        }
}

// ---------------- 5) flash attention: 512 thr, 8 waves x 16 q ----------------
// Same tiles/swizzles as R5; staging split over 8 waves (2 K-dma + 1 V-dma each).
__global__ __attribute__((amdgpu_flat_work_group_size(512, 512),
                          amdgpu_waves_per_eu(4, 4)))
void flash_kernel(const short* __restrict__ Qp,
                  const short* __restrict__ Kp,
                  const short* __restrict__ Vp,
                  short* __restrict__ AO) {
    const int h  = blockIdx.x;
    const int qb = blockIdx.y;
    const int b  = blockIdx.z;
    const int tid  = threadIdx.x;
    const int lane = tid & 63;
    const int w    = tid >> 6;          // wave 0..7, owns 16 q rows
    const int l16  = lane & 15;
    const int quad = lane >> 4;
    const size_t bh = (size_t)(b * 16 + h);

    __shared__ short Ks[16384];   // 2 x 8192 shorts (64 key x 128 d)
    __shared__ short Vs[8192];    // 2 x 4096 shorts (64 d x 64 slot)

    // Q fragment (B-operand): lane l16 -> q row, k = quad*8 + j
    short8 qf[4];
    {
        const short* Qb = Qp + ((bh * 1024 + qb * 128 + w * 16 + l16) << 7) + quad * 8;
        #pragma unroll
        for (int c = 0; c < 4; c++) qf[c] = *(const short8*)(Qb + c * 32);
    }

    // staging sources (source-side swizzle, lane-linear LDS)
    const short* kSrc[2];
    #pragma unroll
    for (int jj = 0; jj < 2; jj++) {
        int key = (w * 2 + jj) * 4 + quad;
        kSrc[jj] = Kp + (bh << 17) + key * 128 + ((l16 ^ (key & 15)) * 8);
    }
    const short* vSrc;
    {
        int d = w * 8 + (lane >> 3);
        vSrc = Vp + (bh << 16) + d * 1024 + (((lane & 7) ^ (d & 7)) * 8);
    }

    int krd[4];
    #pragma unroll
    for (int c = 0; c < 4; c++) krd[c] = l16 * 128 + (((c * 4 + quad) ^ l16) * 8);
    int vrd[2];
    #pragma unroll
    for (int g = 0; g < 2; g++) vrd[g] = l16 * 64 + (((g * 4 + quad) ^ (l16 & 7)) * 8);

    // prologue: tile 0 -> buf 0
    #pragma unroll
    for (int jj = 0; jj < 2; jj++) dma16(kSrc[jj], &Ks[w * 1024 + jj * 512]);
    dma16(vSrc, &Vs[w * 512]);
    #pragma unroll
    for (int jj = 0; jj < 2; jj++) kSrc[jj] += 8192;
    vSrc += 64;
    int dstK = 8192, dstV = 4096;

    float4v zero4 = {0.f, 0.f, 0.f, 0.f};
    float4v o_acc[4];
    #pragma unroll
    for (int mt = 0; mt < 4; mt++) o_acc[mt] = zero4;
    float l_part = 0.f;

    __syncthreads();

    for (int kt = 0; kt < 16; kt++) {
        if (kt < 15) {
            #pragma unroll
            for (int jj = 0; jj < 2; jj++) dma16(kSrc[jj], &Ks[dstK + w * 1024 + jj * 512]);
            dma16(vSrc, &Vs[dstV + w * 512]);
            #pragma unroll
            for (int jj = 0; jj < 2; jj++) kSrc[jj] += 8192;
            vSrc += 64;
            dstK ^= 8192; dstV ^= 4096;
        }

        // S^T = K·Q^T (C-layout: col=l16=q, row=key=mt*16+quad*4+r)
        float4v s[4];
        #pragma unroll
        for (int mt = 0; mt < 4; mt++) {
            short8 kf[4];
            #pragma unroll
            for (int c = 0; c < 4; c++) kf[c] = *(const short8*)&Ks[krd[c] + mt * 2048];
            s[mt] = zero4;
            #pragma unroll
            for (int c = 0; c < 4; c++)
                s[mt] = MFMA16(kf[c], qf[c], s[mt]);
        }

        // p = exp2(s); per-lane partial l
        #pragma unroll
        for (int mt = 0; mt < 4; mt++)
            #pragma unroll
            for (int r = 0; r < 4; r++) {
                float p = __builtin_exp2f(s[mt][r]);
                s[mt][r] = p;
                l_part += p;
            }

        // O^T += V^T · P^T
        #pragma unroll
        for (int g = 0; g < 2; g++) {
            short8 pf;
            #pragma unroll
            for (int j = 0; j < 4; j++) {
                ((unsigned*)&pf)[j >> 1] = 0;  // placeholder, overwritten below
            }
            union { unsigned u[4]; short8 v; } t;
            t.u[0] = pack2bf(s[2 * g][0], s[2 * g][1]);
            t.u[1] = pack2bf(s[2 * g][2], s[2 * g][3]);
            t.u[2] = pack2bf(s[2 * g + 1][0], s[2 * g + 1][1]);
            t.u[3] = pack2bf(s[2 * g + 1][2], s[2 * g + 1][3]);
            pf = t.v;
            #pragma unroll
            for (int mt = 0; mt < 4; mt++) {
                short8 vf = *(const short8*)&Vs[vrd[g] + mt * 1024];
                o_acc[mt] = MFMA16(vf, pf, o_acc[mt]);
            }
        }

        if (kt < 15) __syncthreads();
        #pragma unroll
        for (int c = 0; c < 4; c++) krd[c] ^= 8192;
        #pragma unroll
        for (int g = 0; g < 2; g++) vrd[g] ^= 4096;
    }

    // epilogue: reduce l across quads, normalize, store
    {
        float l = l_part;
        l += __shfl_xor(l, 16, 64);
        l += __shfl_xor(l, 32, 64);
        float inv = 1.0f / l;
        int row = b * 1024 + qb * 128 + w * 16 + l16;
        #pragma unroll
        for (int mt = 0; mt < 4; mt++) {
            short4v ov;
            #pragma unroll
            for (int r = 0; r < 4; r++) ov[r] = f2bf(o_acc[mt][r] * inv);
            *(short4v*)(AO + (size_t)row * 1024 + h * 64 + mt * 16 + quad * 4) = ov;
        }
    }
}

extern "C" void kernel_launch(void* const* d_in, const int* in_sizes, int n_in,
                              void* d_out, int out_size, void* d_ws, size_t ws_size,
                              hipStream_t stream) {
    const float* x    = (const float*)d_in[0];
    const float* harm = (const float*)d_in[1];
    const float* wq   = (const float*)d_in[2];
    const float* bq   = (const float*)d_in[3];
    const float* wk   = (const float*)d_in[4];
    const float* bk   = (const float*)d_in[5];
    const float* wv   = (const float*)d_in[6];
    const float* bv   = (const float*)d_in[7];
    const float* wo   = (const float*)d_in[8];
    const float* bo   = (const float*)d_in[9];
    float* outF = (float*)d_out;

    short* xb   = (short*)d_ws;                 // 4M shorts; ALIASED as AO
    short* Qp   = xb + (size_t)4 * 1048576;     // 8M shorts
    short* Kp   = Qp + (size_t)8 * 1048576;     // 8M shorts
    short* Vp   = Kp + (size_t)8 * 1048576;     // 4M shorts
    short* Wqkv = Vp + (size_t)4 * 1048576;     // 3M shorts (wq,wk,wv)
    short* Wob  = Wqkv + (size_t)3 * 1048576;   // 1M shorts (wo)
    short* AO   = xb;   // alias: xb consumed by QKV GEMM before flash writes AO

    convert_all<<<dim3(2048), dim3(256), 0, stream>>>(x, wq, wk, wv, wo, xb, Wqkv);
    gemm_kernel<0><<<dim3(32, 8, 3), dim3(256), 0, stream>>>(
        xb, Wqkv, bq, bk, bv, Qp, Kp, Vp, nullptr);
    fill_aug<<<dim3(32, 4), dim3(256), 0, stream>>>(harm, Qp, Kp);
    flash_kernel<<<dim3(16, 8, 4), dim3(512), 0, stream>>>(Qp, Kp, Vp, AO);
    gemm_kernel<1><<<dim3(32, 8, 1), dim3(256), 0, stream>>>(
        AO, Wob, bo, nullptr, nullptr, nullptr, nullptr, nullptr, outF);
}